// Round 4
// baseline (171.552 us; speedup 1.0000x reference)
//
#include <hip/hip_runtime.h>

// B=8, T=2048, C=1024, H=64.  Reference: softmax over QUERY axis (dim=1),
// no 1/sqrt(d) scale.  out[t,h] = sum_{s<=t} exp(q_t.k_s)/D_s * v[s,h],
// D_s = sum_{t>=s} exp(q_t.k_s).
// Split-bf16 (hi+lo, 3-term) MFMA for qkv GEMM and QK dots (~fp32 accuracy);
// plain bf16 for V and P in PV (~0.4% rel).
//
// Round-13: stats STORES P = exp(S) (causal-masked, unnormalized, bf16) in
// MFMA A-fragment layout while accumulating D.  vscale folds 1/D_s into V.
// out = pure streaming PV GEMM.  P buffer = 67 MB in ws.
//
// Round-14 (FAILED): M-tile 32 / grid 512: occupancy up but qkv 43->51 us.
// Round-15 (NEUTRAL): reg software-pipeline of FW frags: compiler sank the
// loads back to their uses — source-level reg pipelining defeated.
// Round-16 (BUG): global_load_lds staging; FW chunk stride miswritten as
// kc*1024 (old code's it*1024 encoded chunk 2*it at 512 u16/chunk) ->
// B-fragments read K-chunk 2*kc.  absmax 7.06.
// Round-17: same structure, FW offset fixed to kc*512.

typedef __attribute__((ext_vector_type(8))) short bf16x8;
typedef __attribute__((ext_vector_type(4))) float f32x4;
typedef unsigned short u16;

#define MFMA(a, b, c) __builtin_amdgcn_mfma_f32_16x16x32_bf16((a), (b), (c), 0, 0, 0)

__device__ __forceinline__ u16 f2bf(float x) {           // RNE fp32 -> bf16
    unsigned u = __float_as_uint(x);
    u += 0x7fff + ((u >> 16) & 1);
    return (u16)(u >> 16);
}
__device__ __forceinline__ float bf2f(u16 h) {
    return __uint_as_float(((unsigned)h) << 16);
}

// trunc-split 8 fp32 -> hi bf16x8 + lo bf16x8.  hi = chop(x) (exact residual:
// bf2f(hi) = x & 0xffff0000), lo = chop(x - bf2f(hi)).  Total repr error
// ~2^-16 |x|, same class as the dropped AL*BL term.  ~3 VALU per float.
__device__ __forceinline__ void split8(const f32x4 x0, const f32x4 x1,
                                       bf16x8* hv, bf16x8* lv)
{
    const float f[8] = {x0[0], x0[1], x0[2], x0[3], x1[0], x1[1], x1[2], x1[3]};
    union { unsigned u[4]; bf16x8 v; } H, L;
    #pragma unroll
    for (int j = 0; j < 4; ++j) {
        const unsigned u0 = __float_as_uint(f[2 * j]);
        const unsigned u1 = __float_as_uint(f[2 * j + 1]);
        H.u[j] = __builtin_amdgcn_perm(u1, u0, 0x07060302);   // top16 of each
        const float l0 = f[2 * j]     - __uint_as_float(u0 & 0xffff0000u);
        const float l1 = f[2 * j + 1] - __uint_as_float(u1 & 0xffff0000u);
        L.u[j] = __builtin_amdgcn_perm(__float_as_uint(l1), __float_as_uint(l0),
                                       0x07060302);
    }
    *hv = H.v;
    *lv = L.v;
}

typedef const __attribute__((address_space(1))) void* gas_p;
typedef __attribute__((address_space(3))) void* las_p;

// ws byte offsets
#define WH_OFF  0u
#define WL_OFF  (WH_OFF + 192u*1024u*2u)
#define FQH_OFF (WL_OFF + 192u*1024u*2u)
#define FQL_OFF (FQH_OFF + 2u*1024u*1024u)
#define FKH_OFF (FQL_OFF + 2u*1024u*1024u)
#define FKL_OFF (FKH_OFF + 2u*1024u*1024u)
#define VF_OFF  (FKL_OFF + 2u*1024u*1024u)
#define DD_OFF  (VF_OFF + 2u*1024u*1024u)          // fp32 [B][T] = 64 KB
#define PF_OFF  (DD_OFF + 8u*2048u*4u)             // bf16, 67 MB

// ---------------------------------------------------------------------------
// W pre-split into fragment-coalesced layout (r12 verbatim).
// ---------------------------------------------------------------------------
__global__ __launch_bounds__(128) void wsplit_kernel(
    const float* __restrict__ Wk, const float* __restrict__ Wq,
    const float* __restrict__ Wv, u16* __restrict__ FWH, u16* __restrict__ FWL)
{
    const int n = blockIdx.x;                 // 0..191
    const int nblk = n >> 4, lr = n & 15;
    const float* src = (n < 64) ? (Wq + (long)n * 1024)
                     : (n < 128) ? (Wk + (long)(n - 64) * 1024)
                                 : (Wv + (long)(n - 128) * 1024);
    const int f = threadIdx.x;                // 0..127 fragment id
    const int kc = f >> 2, q = f & 3;
    const float4 f0 = *(const float4*)&src[kc * 32 + q * 8];
    const float4 f1 = *(const float4*)&src[kc * 32 + q * 8 + 4];
    const float vs[8] = {f0.x, f0.y, f0.z, f0.w, f1.x, f1.y, f1.z, f1.w};
    bf16x8 hv, lv;
    #pragma unroll
    for (int j = 0; j < 8; ++j) {
        const u16 h = f2bf(vs[j]);
        hv[j] = (short)h;
        lv[j] = (short)f2bf(vs[j] - bf2f(h));
    }
    const long o = ((long)(nblk * 32 + kc) * 64 + q * 16 + lr) * 8;
    *(bf16x8*)&FWH[o] = hv;
    *(bf16x8*)&FWL[o] = lv;
}

// ---------------------------------------------------------------------------
// qkv.  M-tile 64, 512 thr = 8 waves (2m x 4n), grid 256.  idx staged as
// raw fp32 via global_load_lds (issue-and-forget DMA, cannot be sunk by the
// scheduler), double-buffered, BK=128, 8 barriers.  Source pre-swizzled
// (chunk ^ (row&7)) so linear-dest LDS reads back conflict-reduced.
// Consumer-side trunc-split to AH/AL.  Epilogue writes fragment layouts.
// FW chunk kc (32 K-elems) lives at (nbb+nf)*16384 + kc*512 u16.
// ---------------------------------------------------------------------------
__global__ __launch_bounds__(512, 2) void qkv_kernel(
    const float* __restrict__ idx, const u16* __restrict__ FWH, const u16* __restrict__ FWL,
    u16* __restrict__ FQH, u16* __restrict__ FQL,
    u16* __restrict__ FKH, u16* __restrict__ FKL, u16* __restrict__ VF)
{
    __shared__ float a_f0[64 * 128];           // 32 KB
    __shared__ float a_f1[64 * 128];           // 32 KB
    const int tid = threadIdx.x;
    const int w = tid >> 6, lr = tid & 15, quad = (tid >> 4) & 3;
    const int lane = tid & 63;
    const int r0 = blockIdx.x * 64;
    const int b = r0 >> 11, t0 = r0 & 2047;
    const int m0 = (w & 1) * 32;
    const int nbb = (w >> 1) * 3;

    // Staging geometry: round g stages segment s = g*8+w (1 KB, wave-uniform
    // LDS base, HW adds lane*16B).  Lane covers row = s*2 + (lane>>5),
    // physical 16B-chunk pc = lane&31; logical chunk lc = pc ^ (row&7).
    const float* gsrc[4];
    int lseg[4];
    #pragma unroll
    for (int g = 0; g < 4; ++g) {
        const int s = g * 8 + w;
        const int row = s * 2 + (lane >> 5);
        const int lc = (lane & 31) ^ (row & 7);
        gsrc[g] = idx + (long)(r0 + row) * 1024 + lc * 4;
        lseg[g] = s * 256;                     // float offset of segment base
    }

#define STAGE(BUF, IT)                                                        \
    {                                                                         \
        _Pragma("unroll")                                                     \
        for (int g = 0; g < 4; ++g) {                                         \
            __builtin_amdgcn_global_load_lds(                                 \
                (gas_p)(gsrc[g] + (IT) * 128),                                \
                (las_p)(BUF + lseg[g]), 16, 0, 0);                            \
        }                                                                     \
    }

    f32x4 acc[2][3] = {};

    STAGE(a_f0, 0);
    __syncthreads();

    // One BK=128 iteration reading BUF; prefetches tile IT+1 into NXT.
#define QKV_ITER(IT, BUF, NXT)                                                \
    {                                                                         \
        const int it_ = (IT);                                                 \
        if (it_ < 7) STAGE(NXT, it_ + 1);                                     \
        _Pragma("unroll")                                                     \
        for (int kblk = 0; kblk < 4; ++kblk) {                                \
            const int kc = it_ * 4 + kblk;                                    \
            bf16x8 AH[2], AL[2];                                              \
            _Pragma("unroll")                                                 \
            for (int mi = 0; mi < 2; ++mi) {                                  \
                const int row = m0 + mi * 16 + lr;                            \
                const int pc0 = (kblk * 8 + quad * 2) ^ (lr & 7);             \
                const f32x4 x0 = *(const f32x4*)&BUF[row * 128 + pc0 * 4];    \
                const f32x4 x1 = *(const f32x4*)&BUF[row * 128 + (pc0 ^ 1) * 4]; \
                split8(x0, x1, &AH[mi], &AL[mi]);                             \
            }                                                                 \
            _Pragma("unroll")                                                 \
            for (int nf = 0; nf < 3; ++nf) {                                  \
                const long fb = (long)(nbb + nf) * 16384 + (long)kc * 512     \
                              + lane * 8;                                     \
                const bf16x8 bh = *(const bf16x8*)&FWH[fb];                   \
                const bf16x8 bl = *(const bf16x8*)&FWL[fb];                   \
                _Pragma("unroll")                                             \
                for (int mi = 0; mi < 2; ++mi) {                              \
                    f32x4 c = acc[mi][nf];                                    \
                    c = MFMA(AH[mi], bh, c);                                  \
                    c = MFMA(AL[mi], bh, c);                                  \
                    c = MFMA(AH[mi], bl, c);                                  \
                    acc[mi][nf] = c;                                          \
                }                                                             \
            }                                                                 \
        }                                                                     \
        if (it_ < 7) __syncthreads();                                         \
    }

    for (int it2 = 0; it2 < 4; ++it2) {
        QKV_ITER(2 * it2,     a_f0, a_f1);
        QKV_ITER(2 * it2 + 1, a_f1, a_f0);
    }
#undef QKV_ITER
#undef STAGE

    #pragma unroll
    for (int mi = 0; mi < 2; ++mi) {
        const int tb = t0 + m0 + mi * 16 + quad * 4;
        const int tblk = (t0 + m0 + mi * 16) >> 4;
        #pragma unroll
        for (int nf = 0; nf < 3; ++nf) {
            const int n = (nbb + nf) * 16 + lr;
            const f32x4 a = acc[mi][nf];
            if (n < 128) {
                u16* Hd = (n < 64) ? FQH : FKH;
                u16* Ld = (n < 64) ? FQL : FKL;
                const int h = n & 63;
                const int kc = h >> 5;
                const int lsub = 16 * ((h & 31) >> 3);
                const long base = ((long)(b * 128 + tblk) * 2 + kc) * 512 + (h & 7);
                #pragma unroll
                for (int r = 0; r < 4; ++r) {
                    const float v = a[r];
                    const u16 hi = f2bf(v);
                    const u16 lo = f2bf(v - bf2f(hi));
                    const long o = base + (long)(quad * 4 + r + lsub) * 8;
                    Hd[o] = hi; Ld[o] = lo;
                }
            } else {
                const int h = n - 128;
                const int hblk = h >> 4;
                #pragma unroll
                for (int r = 0; r < 4; ++r) {
                    const int t = tb + r;
                    const long o = ((long)(b * 4 + hblk) * 64 + (t >> 5)) * 512
                                 + (long)(16 * ((t & 31) >> 3) + (h & 15)) * 8 + (t & 7);
                    VF[o] = f2bf(a[r]);
                }
            }
        }
    }
}

// ---------------------------------------------------------------------------
// stats: D_s = sum_{t>=s} exp(q_t.k_s)  AND stores P = exp (masked, bf16)
// into A-fragment layout PF[b][tblk][kc=s/32][lane][8].  K B-frags hoisted,
// Q A-frags per-jt (all fragment-coalesced 1KB loads).  No staging LDS.
// Grid (144, B): s-tile i, t-chunk c (<=4 t-tiles); atomicAdd partials.
// ---------------------------------------------------------------------------
__global__ __launch_bounds__(256, 4) void stats_kernel(
    const u16* __restrict__ FQH, const u16* __restrict__ FQL,
    const u16* __restrict__ FKH, const u16* __restrict__ FKL,
    u16* __restrict__ PF, float* __restrict__ D)
{
    __shared__ float red[4][64];
    const int tid = threadIdx.x;
    const int w = tid >> 6, lr = tid & 15, quad = (tid >> 4) & 3;
    const int lane = tid & 63;
    const int b = blockIdx.y;
    int x = blockIdx.x, i = 0;
    for (;;) { const int nc = (35 - i) >> 2; if (x < nc) break; x -= nc; ++i; }
    const int s0 = i * 64;
    const int jt0 = i + 4 * x, jt1 = min(jt0 + 4, 32);

    bf16x8 BH[4][2], BL[4][2];
    #pragma unroll
    for (int nf = 0; nf < 4; ++nf) {
        const long kb = ((long)(b * 128 + i * 4 + nf) * 2) * 512 + lane * 8;
        BH[nf][0] = *(const bf16x8*)&FKH[kb];
        BH[nf][1] = *(const bf16x8*)&FKH[kb + 512];
        BL[nf][0] = *(const bf16x8*)&FKL[kb];
        BL[nf][1] = *(const bf16x8*)&FKL[kb + 512];
    }

    float dsum[4] = {0.f, 0.f, 0.f, 0.f};
    for (int jt = jt0; jt < jt1; ++jt) {
        const long qb = ((long)(b * 128 + jt * 4 + w) * 2) * 512 + lane * 8;
        const bf16x8 ah0 = *(const bf16x8*)&FQH[qb];
        const bf16x8 ah1 = *(const bf16x8*)&FQH[qb + 512];
        const bf16x8 al0 = *(const bf16x8*)&FQL[qb];
        const bf16x8 al1 = *(const bf16x8*)&FQL[qb + 512];
        const bool diag = (jt == i);
        #pragma unroll
        for (int nf = 0; nf < 4; ++nf) {
            f32x4 cc = {};
            cc = MFMA(ah0, BH[nf][0], cc);
            cc = MFMA(al0, BH[nf][0], cc);
            cc = MFMA(ah0, BL[nf][0], cc);
            cc = MFMA(ah1, BH[nf][1], cc);
            cc = MFMA(al1, BH[nf][1], cc);
            cc = MFMA(ah1, BL[nf][1], cc);

            // P store base: t = jt*64 + w*16 + quad*4 + r, s = i*64 + nf*16 + lr
            const long pbase = ((long)(b * 128 + jt * 4 + w) * 64 + i * 2 + (nf >> 1)) * 512
                             + (long)(((nf & 1) * 2 + (lr >> 3)) * 16) * 8 + (lr & 7);
            const int sl = nf * 16 + lr;
            #pragma unroll
            for (int r = 0; r < 4; ++r) {
                float ev = __expf(cc[r]);
                if (diag && (w * 16 + quad * 4 + r < sl)) ev = 0.f;
                dsum[nf] += ev;
                PF[pbase + (long)(quad * 4 + r) * 8] = f2bf(ev);
            }
        }
    }

    #pragma unroll
    for (int nf = 0; nf < 4; ++nf) {
        dsum[nf] += __shfl_xor(dsum[nf], 16);
        dsum[nf] += __shfl_xor(dsum[nf], 32);
    }
    if (quad == 0) {
        #pragma unroll
        for (int nf = 0; nf < 4; ++nf) red[w][nf * 16 + lr] = dsum[nf];
    }
    __syncthreads();
    if (tid < 64)
        atomicAdd(&D[b * 2048 + s0 + tid],
                  red[0][tid] + red[1][tid] + red[2][tid] + red[3][tid]);
}

// ---------------------------------------------------------------------------
// vscale: VF (B-fragment layout) *= 1/D[s].  Entry (b,hblk,kc,lane,j) has
// s = kc*32 + (lane>>4)*8 + j  (j consecutive in s).
// ---------------------------------------------------------------------------
__global__ __launch_bounds__(256) void vscale_kernel(
    u16* __restrict__ VF, const float* __restrict__ D)
{
    const int g = blockIdx.x * 256 + threadIdx.x;   // 131072 threads x 8 u16
    const long e = (long)g * 8;
    const int lane = (int)((e >> 3) & 63);
    const int kc   = (int)((e >> 9) & 63);
    const int b    = (int)(e >> 17);
    const int s = kc * 32 + (lane >> 4) * 8;
    const float4 d0 = *(const float4*)&D[b * 2048 + s];
    const float4 d1 = *(const float4*)&D[b * 2048 + s + 4];
    const float dv[8] = {d0.x, d0.y, d0.z, d0.w, d1.x, d1.y, d1.z, d1.w};
    bf16x8 vv = *(bf16x8*)&VF[e];
    bf16x8 ov;
    #pragma unroll
    for (int j = 0; j < 8; ++j)
        ov[j] = (short)f2bf(bf2f((u16)vv[j]) / dv[j]);
    *(bf16x8*)&VF[e] = ov;
}

// ---------------------------------------------------------------------------
// out: pure streaming PV GEMM.  out[t][h] = sum_{s<=t} P[t][s] * Vtilde[s][h].
// Per s-tile: 2 P A-frag loads + 8 V B-frag loads + 8 MFMA.  No LDS, no
// barriers, no exp.  Grid (80, B): t-tile i, s-chunk c (<=8 s-tiles).
// ---------------------------------------------------------------------------
__global__ __launch_bounds__(256, 4) void out_kernel(
    const u16* __restrict__ PF, const u16* __restrict__ VF,
    float* __restrict__ out)
{
    const int tid = threadIdx.x;
    const int w = tid >> 6, lr = tid & 15, quad = (tid >> 4) & 3;
    const int lane = tid & 63;
    const int b = blockIdx.y;
    int x = blockIdx.x, i = 0;
    for (;;) { const int nc = (i + 8) >> 3; if (x < nc) break; x -= nc; ++i; }
    const int t0 = i * 64;
    const int js0 = 8 * x, js1 = min(8 * x + 8, i + 1);
    const int tblk = i * 4 + w;

    f32x4 oacc[4] = {};
    for (int js = js0; js < js1; ++js) {
        const long pb = ((long)(b * 128 + tblk) * 64 + 2 * js) * 512 + lane * 8;
        const bf16x8 a0 = *(const bf16x8*)&PF[pb];
        const bf16x8 a1 = *(const bf16x8*)&PF[pb + 512];
        #pragma unroll
        for (int nf = 0; nf < 4; ++nf) {
            const long vb = ((long)(b * 4 + nf) * 64 + 2 * js) * 512 + lane * 8;
            const bf16x8 v0 = *(const bf16x8*)&VF[vb];
            const bf16x8 v1 = *(const bf16x8*)&VF[vb + 512];
            oacc[nf] = MFMA(a0, v0, oacc[nf]);
            oacc[nf] = MFMA(a1, v1, oacc[nf]);
        }
    }

    const bool single = (i < 8);   // one chunk covers the whole row
    #pragma unroll
    for (int nf = 0; nf < 4; ++nf) {
        const int h = nf * 16 + lr;
        #pragma unroll
        for (int r = 0; r < 4; ++r) {
            const int t = t0 + w * 16 + quad * 4 + r;
            const long o = (long)(b * 2048 + t) * 64 + h;
            if (single) out[o] = oacc[nf][r];
            else        atomicAdd(&out[o], oacc[nf][r]);
        }
    }
}

extern "C" void kernel_launch(void* const* d_in, const int* in_sizes, int n_in,
                              void* d_out, int out_size, void* d_ws, size_t ws_size,
                              hipStream_t stream)
{
    const float* idx = (const float*)d_in[0];
    const float* Wk  = (const float*)d_in[1];
    const float* Wq  = (const float*)d_in[2];
    const float* Wv  = (const float*)d_in[3];
    char* ws = (char*)d_ws;
    float* out = (float*)d_out;

    u16* FWH = (u16*)(ws + WH_OFF);  u16* FWL = (u16*)(ws + WL_OFF);
    u16* FQH = (u16*)(ws + FQH_OFF); u16* FQL = (u16*)(ws + FQL_OFF);
    u16* FKH = (u16*)(ws + FKH_OFF); u16* FKL = (u16*)(ws + FKL_OFF);
    u16* VF  = (u16*)(ws + VF_OFF);
    float* Dp = (float*)(ws + DD_OFF);
    u16* PF  = (u16*)(ws + PF_OFF);

    hipMemsetAsync(out, 0, (size_t)8 * 2048 * 64 * sizeof(float), stream);
    hipMemsetAsync(Dp, 0, (size_t)8 * 2048 * sizeof(float), stream);

    wsplit_kernel<<<192, 128, 0, stream>>>(Wk, Wq, Wv, FWH, FWL);
    qkv_kernel<<<256, 512, 0, stream>>>(idx, FWH, FWL, FQH, FQL, FKH, FKL, VF);
    stats_kernel<<<dim3(144, 8), 256, 0, stream>>>(FQH, FQL, FKH, FKL, PF, Dp);
    vscale_kernel<<<512, 256, 0, stream>>>(VF, Dp);
    out_kernel<<<dim3(80, 8), 256, 0, stream>>>(PF, VF, out);
}

// Round 5
// 163.082 us; speedup vs baseline: 1.0519x; 1.0519x over previous
//
#include <hip/hip_runtime.h>

// B=8, T=2048, C=1024, H=64.  Reference: softmax over QUERY axis (dim=1),
// no 1/sqrt(d) scale.  out[t,h] = sum_{s<=t} exp(q_t.k_s)/D_s * v[s,h],
// D_s = sum_{t>=s} exp(q_t.k_s).
// Split-bf16 (hi+lo, 3-term) MFMA for qkv GEMM and QK dots (~fp32 accuracy);
// plain bf16 for V and P in PV (~0.4% rel).
//
// Round-13: stats stores P=exp (masked, bf16, A-frag layout) while summing D;
// vscale folds 1/D into V; out = pure streaming PV GEMM.  qkv = 43 us.
// Round-14 (FAILED 51us): M32/grid512 — occupancy up, FW L2 traffic doubled.
// Round-15 (NEUTRAL): reg-pipelined FW — compiler sank the loads (VGPR 64).
// Round-16/17 (48us): DMA A-staging + BK=128 — A was never the problem.
// Round-18: the common residual of all variants is the FW (B-operand) stream:
// 12 KB/iter/wave of global dwordx4 from L2 straight into the MFMA dep chain,
// 2 waves/SIMD.  Per m97/m151 (874 vs 646 TF): stream B through LDS via
// global_load_lds.  FW slice (48 KB/iter) DMA'd double-buffered (48 x 1KB
// wave-segments, linear dest — source already fragment-coalesced); waves
// ds_read_b128 fragments from LDS.  A path identical to the 43us r13.
// FW global traffic also halves (no 2-wave redundancy): 393 -> 196 MB.

typedef __attribute__((ext_vector_type(8))) short bf16x8;
typedef __attribute__((ext_vector_type(4))) float f32x4;
typedef unsigned short u16;

#define MFMA(a, b, c) __builtin_amdgcn_mfma_f32_16x16x32_bf16((a), (b), (c), 0, 0, 0)

__device__ __forceinline__ u16 f2bf(float x) {           // RNE fp32 -> bf16
    unsigned u = __float_as_uint(x);
    u += 0x7fff + ((u >> 16) & 1);
    return (u16)(u >> 16);
}
__device__ __forceinline__ float bf2f(u16 h) {
    return __uint_as_float(((unsigned)h) << 16);
}

typedef const __attribute__((address_space(1))) void* gas_p;
typedef __attribute__((address_space(3))) void* las_p;

// ws byte offsets
#define WH_OFF  0u
#define WL_OFF  (WH_OFF + 192u*1024u*2u)
#define FQH_OFF (WL_OFF + 192u*1024u*2u)
#define FQL_OFF (FQH_OFF + 2u*1024u*1024u)
#define FKH_OFF (FQL_OFF + 2u*1024u*1024u)
#define FKL_OFF (FKH_OFF + 2u*1024u*1024u)
#define VF_OFF  (FKL_OFF + 2u*1024u*1024u)
#define DD_OFF  (VF_OFF + 2u*1024u*1024u)          // fp32 [B][T] = 64 KB
#define PF_OFF  (DD_OFF + 8u*2048u*4u)             // bf16, 67 MB

// ---------------------------------------------------------------------------
// W pre-split into fragment-coalesced layout (r12 verbatim).
// FW chunk kc (32 K-elems) of col-block nblk lives at nblk*16384 + kc*512 u16.
// ---------------------------------------------------------------------------
__global__ __launch_bounds__(128) void wsplit_kernel(
    const float* __restrict__ Wk, const float* __restrict__ Wq,
    const float* __restrict__ Wv, u16* __restrict__ FWH, u16* __restrict__ FWL)
{
    const int n = blockIdx.x;                 // 0..191
    const int nblk = n >> 4, lr = n & 15;
    const float* src = (n < 64) ? (Wq + (long)n * 1024)
                     : (n < 128) ? (Wk + (long)(n - 64) * 1024)
                                 : (Wv + (long)(n - 128) * 1024);
    const int f = threadIdx.x;                // 0..127 fragment id
    const int kc = f >> 2, q = f & 3;
    const float4 f0 = *(const float4*)&src[kc * 32 + q * 8];
    const float4 f1 = *(const float4*)&src[kc * 32 + q * 8 + 4];
    const float vs[8] = {f0.x, f0.y, f0.z, f0.w, f1.x, f1.y, f1.z, f1.w};
    bf16x8 hv, lv;
    #pragma unroll
    for (int j = 0; j < 8; ++j) {
        const u16 h = f2bf(vs[j]);
        hv[j] = (short)h;
        lv[j] = (short)f2bf(vs[j] - bf2f(h));
    }
    const long o = ((long)(nblk * 32 + kc) * 64 + q * 16 + lr) * 8;
    *(bf16x8*)&FWH[o] = hv;
    *(bf16x8*)&FWL[o] = lv;
}

// ---------------------------------------------------------------------------
// qkv.  M-tile 64, 512 thr = 8 waves (2m x 4n), grid 256.  A-tile dbuf LDS
// (bf16 hi/lo, stage-side convert — r13 path).  FW slice dbuf LDS via
// global_load_lds DMA: 48 segs of 1KB per iter (seg = nblk*4+kcpar*2+hl),
// wave w stages segs w*6..w*6+5; fragments then read via ds_read_b128.
// One __syncthreads per iter drains both DMA (vmcnt) and ds_writes.
// ---------------------------------------------------------------------------
__global__ __launch_bounds__(512, 2) void qkv_kernel(
    const float* __restrict__ idx, const u16* __restrict__ FWH, const u16* __restrict__ FWL,
    u16* __restrict__ FQH, u16* __restrict__ FQL,
    u16* __restrict__ FKH, u16* __restrict__ FKL, u16* __restrict__ VF)
{
    __shared__ u16 a_l[2][64 * 136];          // 34.8 KB
    __shared__ u16 fw_l[2][48 * 512];         // 96 KB
    const int tid = threadIdx.x;
    const int w = tid >> 6, lr = tid & 15, quad = (tid >> 4) & 3;
    const int lane = tid & 63;
    const int r0 = blockIdx.x * 64;
    const int b = r0 >> 11, t0 = r0 & 2047;
    const int m0 = (w & 1) * 32;
    const int nbb = (w >> 1) * 3;
    const int sr = tid >> 3, sc = (tid & 7) * 8;
    const float* arow = &idx[(long)(r0 + sr) * 1024 + sc];

    // FW DMA geometry: seg = nblk*4 + kcpar*2 + hl; iter it covers kc=2it+kcpar.
    const u16* fsrc[6];
    int fdst[6];
    #pragma unroll
    for (int j = 0; j < 6; ++j) {
        const int seg = w * 6 + j;
        const int nblk = seg >> 2, kcpar = (seg >> 1) & 1, hl = seg & 1;
        const u16* base = hl ? FWL : FWH;
        fsrc[j] = base + (long)nblk * 16384 + kcpar * 512 + lane * 8;
        fdst[j] = seg * 512;
    }

#define STAGE_FW(P, IT)                                                       \
    {                                                                         \
        _Pragma("unroll")                                                     \
        for (int j = 0; j < 6; ++j)                                           \
            __builtin_amdgcn_global_load_lds(                                 \
                (gas_p)(fsrc[j] + (long)(IT) * 1024),                         \
                (las_p)&fw_l[P][fdst[j]], 16, 0, 0);                          \
    }

    f32x4 acc[2][3] = {};
    float4 pf0, pf1;

    STAGE_FW(0, 0);
    pf0 = *(const float4*)(arow);
    pf1 = *(const float4*)(arow + 4);
    {
        const float vs[8] = {pf0.x, pf0.y, pf0.z, pf0.w, pf1.x, pf1.y, pf1.z, pf1.w};
        bf16x8 hv, lv;
        #pragma unroll
        for (int j = 0; j < 8; ++j) {
            const u16 h = f2bf(vs[j]);
            hv[j] = (short)h;
            lv[j] = (short)f2bf(vs[j] - bf2f(h));
        }
        *(bf16x8*)&a_l[0][sr * 136 + sc]      = hv;
        *(bf16x8*)&a_l[0][sr * 136 + 64 + sc] = lv;
    }
    __syncthreads();

    int p = 0;
    for (int it = 0; it < 16; ++it) {
        if (it < 15) {
            pf0 = *(const float4*)(arow + it * 64 + 64);
            pf1 = *(const float4*)(arow + it * 64 + 68);
            STAGE_FW(p ^ 1, it + 1);
        }

        bf16x8 AH[2][2], AL[2][2];
        #pragma unroll
        for (int mi = 0; mi < 2; ++mi) {
            const int ar = (m0 + mi * 16 + lr) * 136 + quad * 8;
            AH[mi][0] = *(const bf16x8*)&a_l[p][ar];
            AH[mi][1] = *(const bf16x8*)&a_l[p][ar + 32];
            AL[mi][0] = *(const bf16x8*)&a_l[p][ar + 64];
            AL[mi][1] = *(const bf16x8*)&a_l[p][ar + 96];
        }

        #pragma unroll
        for (int nf = 0; nf < 3; ++nf) {
            const int sb = ((nbb + nf) * 4) * 512 + lane * 8;
            const bf16x8 bh0 = *(const bf16x8*)&fw_l[p][sb];
            const bf16x8 bl0 = *(const bf16x8*)&fw_l[p][sb + 512];
            const bf16x8 bh1 = *(const bf16x8*)&fw_l[p][sb + 1024];
            const bf16x8 bl1 = *(const bf16x8*)&fw_l[p][sb + 1536];
            #pragma unroll
            for (int mi = 0; mi < 2; ++mi) {
                f32x4 c = acc[mi][nf];
                c = MFMA(AH[mi][0], bh0, c);
                c = MFMA(AL[mi][0], bh0, c);
                c = MFMA(AH[mi][0], bl0, c);
                c = MFMA(AH[mi][1], bh1, c);
                c = MFMA(AL[mi][1], bh1, c);
                c = MFMA(AH[mi][1], bl1, c);
                acc[mi][nf] = c;
            }
        }

        if (it < 15) {
            const float vs[8] = {pf0.x, pf0.y, pf0.z, pf0.w, pf1.x, pf1.y, pf1.z, pf1.w};
            bf16x8 hv, lv;
            #pragma unroll
            for (int j = 0; j < 8; ++j) {
                const u16 h = f2bf(vs[j]);
                hv[j] = (short)h;
                lv[j] = (short)f2bf(vs[j] - bf2f(h));
            }
            *(bf16x8*)&a_l[p ^ 1][sr * 136 + sc]      = hv;
            *(bf16x8*)&a_l[p ^ 1][sr * 136 + 64 + sc] = lv;
            __syncthreads();
            p ^= 1;
        }
    }
#undef STAGE_FW

    #pragma unroll
    for (int mi = 0; mi < 2; ++mi) {
        const int tb = t0 + m0 + mi * 16 + quad * 4;
        const int tblk = (t0 + m0 + mi * 16) >> 4;
        #pragma unroll
        for (int nf = 0; nf < 3; ++nf) {
            const int n = (nbb + nf) * 16 + lr;
            const f32x4 a = acc[mi][nf];
            if (n < 128) {
                u16* Hd = (n < 64) ? FQH : FKH;
                u16* Ld = (n < 64) ? FQL : FKL;
                const int h = n & 63;
                const int kc = h >> 5;
                const int lsub = 16 * ((h & 31) >> 3);
                const long base = ((long)(b * 128 + tblk) * 2 + kc) * 512 + (h & 7);
                #pragma unroll
                for (int r = 0; r < 4; ++r) {
                    const float v = a[r];
                    const u16 hi = f2bf(v);
                    const u16 lo = f2bf(v - bf2f(hi));
                    const long o = base + (long)(quad * 4 + r + lsub) * 8;
                    Hd[o] = hi; Ld[o] = lo;
                }
            } else {
                const int h = n - 128;
                const int hblk = h >> 4;
                #pragma unroll
                for (int r = 0; r < 4; ++r) {
                    const int t = tb + r;
                    const long o = ((long)(b * 4 + hblk) * 64 + (t >> 5)) * 512
                                 + (long)(16 * ((t & 31) >> 3) + (h & 15)) * 8 + (t & 7);
                    VF[o] = f2bf(a[r]);
                }
            }
        }
    }
}

// ---------------------------------------------------------------------------
// stats: D_s = sum_{t>=s} exp(q_t.k_s)  AND stores P = exp (masked, bf16)
// into A-fragment layout PF[b][tblk][kc=s/32][lane][8].  K B-frags hoisted,
// Q A-frags per-jt (all fragment-coalesced 1KB loads).  No staging LDS.
// Grid (144, B): s-tile i, t-chunk c (<=4 t-tiles); atomicAdd partials.
// ---------------------------------------------------------------------------
__global__ __launch_bounds__(256, 4) void stats_kernel(
    const u16* __restrict__ FQH, const u16* __restrict__ FQL,
    const u16* __restrict__ FKH, const u16* __restrict__ FKL,
    u16* __restrict__ PF, float* __restrict__ D)
{
    __shared__ float red[4][64];
    const int tid = threadIdx.x;
    const int w = tid >> 6, lr = tid & 15, quad = (tid >> 4) & 3;
    const int lane = tid & 63;
    const int b = blockIdx.y;
    int x = blockIdx.x, i = 0;
    for (;;) { const int nc = (35 - i) >> 2; if (x < nc) break; x -= nc; ++i; }
    const int s0 = i * 64;
    const int jt0 = i + 4 * x, jt1 = min(jt0 + 4, 32);

    bf16x8 BH[4][2], BL[4][2];
    #pragma unroll
    for (int nf = 0; nf < 4; ++nf) {
        const long kb = ((long)(b * 128 + i * 4 + nf) * 2) * 512 + lane * 8;
        BH[nf][0] = *(const bf16x8*)&FKH[kb];
        BH[nf][1] = *(const bf16x8*)&FKH[kb + 512];
        BL[nf][0] = *(const bf16x8*)&FKL[kb];
        BL[nf][1] = *(const bf16x8*)&FKL[kb + 512];
    }

    float dsum[4] = {0.f, 0.f, 0.f, 0.f};
    for (int jt = jt0; jt < jt1; ++jt) {
        const long qb = ((long)(b * 128 + jt * 4 + w) * 2) * 512 + lane * 8;
        const bf16x8 ah0 = *(const bf16x8*)&FQH[qb];
        const bf16x8 ah1 = *(const bf16x8*)&FQH[qb + 512];
        const bf16x8 al0 = *(const bf16x8*)&FQL[qb];
        const bf16x8 al1 = *(const bf16x8*)&FQL[qb + 512];
        const bool diag = (jt == i);
        #pragma unroll
        for (int nf = 0; nf < 4; ++nf) {
            f32x4 cc = {};
            cc = MFMA(ah0, BH[nf][0], cc);
            cc = MFMA(al0, BH[nf][0], cc);
            cc = MFMA(ah0, BL[nf][0], cc);
            cc = MFMA(ah1, BH[nf][1], cc);
            cc = MFMA(al1, BH[nf][1], cc);
            cc = MFMA(ah1, BL[nf][1], cc);

            // P store base: t = jt*64 + w*16 + quad*4 + r, s = i*64 + nf*16 + lr
            const long pbase = ((long)(b * 128 + jt * 4 + w) * 64 + i * 2 + (nf >> 1)) * 512
                             + (long)(((nf & 1) * 2 + (lr >> 3)) * 16) * 8 + (lr & 7);
            const int sl = nf * 16 + lr;
            #pragma unroll
            for (int r = 0; r < 4; ++r) {
                float ev = __expf(cc[r]);
                if (diag && (w * 16 + quad * 4 + r < sl)) ev = 0.f;
                dsum[nf] += ev;
                PF[pbase + (long)(quad * 4 + r) * 8] = f2bf(ev);
            }
        }
    }

    #pragma unroll
    for (int nf = 0; nf < 4; ++nf) {
        dsum[nf] += __shfl_xor(dsum[nf], 16);
        dsum[nf] += __shfl_xor(dsum[nf], 32);
    }
    if (quad == 0) {
        #pragma unroll
        for (int nf = 0; nf < 4; ++nf) red[w][nf * 16 + lr] = dsum[nf];
    }
    __syncthreads();
    if (tid < 64)
        atomicAdd(&D[b * 2048 + s0 + tid],
                  red[0][tid] + red[1][tid] + red[2][tid] + red[3][tid]);
}

// ---------------------------------------------------------------------------
// vscale: VF (B-fragment layout) *= 1/D[s].  Entry (b,hblk,kc,lane,j) has
// s = kc*32 + (lane>>4)*8 + j  (j consecutive in s).
// ---------------------------------------------------------------------------
__global__ __launch_bounds__(256) void vscale_kernel(
    u16* __restrict__ VF, const float* __restrict__ D)
{
    const int g = blockIdx.x * 256 + threadIdx.x;   // 131072 threads x 8 u16
    const long e = (long)g * 8;
    const int lane = (int)((e >> 3) & 63);
    const int kc   = (int)((e >> 9) & 63);
    const int b    = (int)(e >> 17);
    const int s = kc * 32 + (lane >> 4) * 8;
    const float4 d0 = *(const float4*)&D[b * 2048 + s];
    const float4 d1 = *(const float4*)&D[b * 2048 + s + 4];
    const float dv[8] = {d0.x, d0.y, d0.z, d0.w, d1.x, d1.y, d1.z, d1.w};
    bf16x8 vv = *(bf16x8*)&VF[e];
    bf16x8 ov;
    #pragma unroll
    for (int j = 0; j < 8; ++j)
        ov[j] = (short)f2bf(bf2f((u16)vv[j]) / dv[j]);
    *(bf16x8*)&VF[e] = ov;
}

// ---------------------------------------------------------------------------
// out: pure streaming PV GEMM.  out[t][h] = sum_{s<=t} P[t][s] * Vtilde[s][h].
// Per s-tile: 2 P A-frag loads + 8 V B-frag loads + 8 MFMA.  No LDS, no
// barriers, no exp.  Grid (80, B): t-tile i, s-chunk c (<=8 s-tiles).
// ---------------------------------------------------------------------------
__global__ __launch_bounds__(256, 4) void out_kernel(
    const u16* __restrict__ PF, const u16* __restrict__ VF,
    float* __restrict__ out)
{
    const int tid = threadIdx.x;
    const int w = tid >> 6, lr = tid & 15, quad = (tid >> 4) & 3;
    const int lane = tid & 63;
    const int b = blockIdx.y;
    int x = blockIdx.x, i = 0;
    for (;;) { const int nc = (i + 8) >> 3; if (x < nc) break; x -= nc; ++i; }
    const int t0 = i * 64;
    const int js0 = 8 * x, js1 = min(8 * x + 8, i + 1);
    const int tblk = i * 4 + w;

    f32x4 oacc[4] = {};
    for (int js = js0; js < js1; ++js) {
        const long pb = ((long)(b * 128 + tblk) * 64 + 2 * js) * 512 + lane * 8;
        const bf16x8 a0 = *(const bf16x8*)&PF[pb];
        const bf16x8 a1 = *(const bf16x8*)&PF[pb + 512];
        #pragma unroll
        for (int nf = 0; nf < 4; ++nf) {
            const long vb = ((long)(b * 4 + nf) * 64 + 2 * js) * 512 + lane * 8;
            const bf16x8 v0 = *(const bf16x8*)&VF[vb];
            const bf16x8 v1 = *(const bf16x8*)&VF[vb + 512];
            oacc[nf] = MFMA(a0, v0, oacc[nf]);
            oacc[nf] = MFMA(a1, v1, oacc[nf]);
        }
    }

    const bool single = (i < 8);   // one chunk covers the whole row
    #pragma unroll
    for (int nf = 0; nf < 4; ++nf) {
        const int h = nf * 16 + lr;
        #pragma unroll
        for (int r = 0; r < 4; ++r) {
            const int t = t0 + w * 16 + quad * 4 + r;
            const long o = (long)(b * 2048 + t) * 64 + h;
            if (single) out[o] = oacc[nf][r];
            else        atomicAdd(&out[o], oacc[nf][r]);
        }
    }
}

extern "C" void kernel_launch(void* const* d_in, const int* in_sizes, int n_in,
                              void* d_out, int out_size, void* d_ws, size_t ws_size,
                              hipStream_t stream)
{
    const float* idx = (const float*)d_in[0];
    const float* Wk  = (const float*)d_in[1];
    const float* Wq  = (const float*)d_in[2];
    const float* Wv  = (const float*)d_in[3];
    char* ws = (char*)d_ws;
    float* out = (float*)d_out;

    u16* FWH = (u16*)(ws + WH_OFF);  u16* FWL = (u16*)(ws + WL_OFF);
    u16* FQH = (u16*)(ws + FQH_OFF); u16* FQL = (u16*)(ws + FQL_OFF);
    u16* FKH = (u16*)(ws + FKH_OFF); u16* FKL = (u16*)(ws + FKL_OFF);
    u16* VF  = (u16*)(ws + VF_OFF);
    float* Dp = (float*)(ws + DD_OFF);
    u16* PF  = (u16*)(ws + PF_OFF);

    hipMemsetAsync(out, 0, (size_t)8 * 2048 * 64 * sizeof(float), stream);
    hipMemsetAsync(Dp, 0, (size_t)8 * 2048 * sizeof(float), stream);

    wsplit_kernel<<<192, 128, 0, stream>>>(Wk, Wq, Wv, FWH, FWL);
    qkv_kernel<<<256, 512, 0, stream>>>(idx, FWH, FWL, FQH, FQL, FKH, FKL, VF);
    stats_kernel<<<dim3(144, 8), 256, 0, stream>>>(FQH, FQL, FKH, FKL, PF, Dp);
    vscale_kernel<<<512, 256, 0, stream>>>(VF, Dp);
    out_kernel<<<dim3(80, 8), 256, 0, stream>>>(PF, VF, out);
}

// Round 6
// 161.842 us; speedup vs baseline: 1.0600x; 1.0077x over previous
//
#include <hip/hip_runtime.h>

// B=8, T=2048, C=1024, H=64.  Reference: softmax over QUERY axis (dim=1),
// no 1/sqrt(d) scale.  out[t,h] = sum_{s<=t} exp(q_t.k_s)/D_s * v[s,h],
// D_s = sum_{t>=s} exp(q_t.k_s).
// Split-bf16 (hi+lo, 3-term) MFMA for qkv GEMM and QK dots (~fp32 accuracy);
// plain bf16 for V and P in PV (~0.4% rel).
//
// Round-13..18 history: every qkv variant (reg-streamed FW, DMA A, FW->LDS)
// lands at 42+-1 us, MfmaUtil ~16%: the __syncthreads() per K-step drains
// vmcnt(0) -> all prefetch latency exposed every iteration (m97-structure
// ceiling).  Round-19 = T3+T4: counted-vmcnt pipeline.  All staging is
// global_load_lds DMA (A raw fp32 w/ swizzled source + consumer split8; FW
// fragment-linear).  Phase = K=32, 4 DMA/wave/phase, quad-buffered 128 KB
// LDS, lookahead 3 phases, boundary = s_waitcnt vmcnt(8) + bare s_barrier
// (never vmcnt(0) in the loop).  No ds_writes -> no lgkm drain at barrier.

typedef __attribute__((ext_vector_type(8))) short bf16x8;
typedef __attribute__((ext_vector_type(4))) float f32x4;
typedef unsigned short u16;

#define MFMA(a, b, c) __builtin_amdgcn_mfma_f32_16x16x32_bf16((a), (b), (c), 0, 0, 0)

__device__ __forceinline__ u16 f2bf(float x) {           // RNE fp32 -> bf16
    unsigned u = __float_as_uint(x);
    u += 0x7fff + ((u >> 16) & 1);
    return (u16)(u >> 16);
}
__device__ __forceinline__ float bf2f(u16 h) {
    return __uint_as_float(((unsigned)h) << 16);
}

// trunc-split 8 fp32 -> hi bf16x8 + lo bf16x8.  hi = chop(x), lo = chop(x -
// bf2f(hi)) (exact residual).  ~3 VALU/float.  Verified r17 (absmax 0.031).
__device__ __forceinline__ void split8(const f32x4 x0, const f32x4 x1,
                                       bf16x8* hv, bf16x8* lv)
{
    const float f[8] = {x0[0], x0[1], x0[2], x0[3], x1[0], x1[1], x1[2], x1[3]};
    union { unsigned u[4]; bf16x8 v; } H, L;
    #pragma unroll
    for (int j = 0; j < 4; ++j) {
        const unsigned u0 = __float_as_uint(f[2 * j]);
        const unsigned u1 = __float_as_uint(f[2 * j + 1]);
        H.u[j] = __builtin_amdgcn_perm(u1, u0, 0x07060302);   // top16 of each
        const float l0 = f[2 * j]     - __uint_as_float(u0 & 0xffff0000u);
        const float l1 = f[2 * j + 1] - __uint_as_float(u1 & 0xffff0000u);
        L.u[j] = __builtin_amdgcn_perm(__float_as_uint(l1), __float_as_uint(l0),
                                       0x07060302);
    }
    *hv = H.v;
    *lv = L.v;
}

typedef const __attribute__((address_space(1))) void* gas_p;
typedef __attribute__((address_space(3))) void* las_p;

// ws byte offsets
#define WH_OFF  0u
#define WL_OFF  (WH_OFF + 192u*1024u*2u)
#define FQH_OFF (WL_OFF + 192u*1024u*2u)
#define FQL_OFF (FQH_OFF + 2u*1024u*1024u)
#define FKH_OFF (FQL_OFF + 2u*1024u*1024u)
#define FKL_OFF (FKH_OFF + 2u*1024u*1024u)
#define VF_OFF  (FKL_OFF + 2u*1024u*1024u)
#define DD_OFF  (VF_OFF + 2u*1024u*1024u)          // fp32 [B][T] = 64 KB
#define PF_OFF  (DD_OFF + 8u*2048u*4u)             // bf16, 67 MB

// ---------------------------------------------------------------------------
// W pre-split into fragment-coalesced layout (r12 verbatim).
// FW chunk kc (32 K-elems) of col-block nblk lives at nblk*16384 + kc*512 u16.
// ---------------------------------------------------------------------------
__global__ __launch_bounds__(128) void wsplit_kernel(
    const float* __restrict__ Wk, const float* __restrict__ Wq,
    const float* __restrict__ Wv, u16* __restrict__ FWH, u16* __restrict__ FWL)
{
    const int n = blockIdx.x;                 // 0..191
    const int nblk = n >> 4, lr = n & 15;
    const float* src = (n < 64) ? (Wq + (long)n * 1024)
                     : (n < 128) ? (Wk + (long)(n - 64) * 1024)
                                 : (Wv + (long)(n - 128) * 1024);
    const int f = threadIdx.x;                // 0..127 fragment id
    const int kc = f >> 2, q = f & 3;
    const float4 f0 = *(const float4*)&src[kc * 32 + q * 8];
    const float4 f1 = *(const float4*)&src[kc * 32 + q * 8 + 4];
    const float vs[8] = {f0.x, f0.y, f0.z, f0.w, f1.x, f1.y, f1.z, f1.w};
    bf16x8 hv, lv;
    #pragma unroll
    for (int j = 0; j < 8; ++j) {
        const u16 h = f2bf(vs[j]);
        hv[j] = (short)h;
        lv[j] = (short)f2bf(vs[j] - bf2f(h));
    }
    const long o = ((long)(nblk * 32 + kc) * 64 + q * 16 + lr) * 8;
    *(bf16x8*)&FWH[o] = hv;
    *(bf16x8*)&FWL[o] = lv;
}

// ---------------------------------------------------------------------------
// qkv.  M-tile 64, 512 thr = 8 waves (2m x 4n), grid 256.  Counted-vmcnt
// DMA pipeline: phase = K=32; per wave per phase 4 global_load_lds (1 A fp32
// seg + 3 FW segs); quad-buffered 32 KB stages (128 KB LDS); lookahead 3.
// Boundary: s_waitcnt vmcnt(8) (tail 4/0) + bare s_barrier.  A source is
// chunk-swizzled (^row&7) so linear-dest LDS reads back conflict-free;
// consumer split8 makes AH/AL.  Epilogue writes fragment layouts.
// ---------------------------------------------------------------------------
__global__ __launch_bounds__(512, 2) void qkv_kernel(
    const float* __restrict__ idx, const u16* __restrict__ FWH, const u16* __restrict__ FWL,
    u16* __restrict__ FQH, u16* __restrict__ FQL,
    u16* __restrict__ FKH, u16* __restrict__ FKL, u16* __restrict__ VF)
{
    __shared__ __align__(16) char smem[4][32768];   // per stage: A 8KB + FW 24KB
    const int tid = threadIdx.x;
    const int w = tid >> 6, lr = tid & 15, quad = (tid >> 4) & 3;
    const int lane = tid & 63;
    const int r0 = blockIdx.x * 64;
    const int b = r0 >> 11, t0 = r0 & 2047;
    const int m0 = (w & 1) * 32;
    const int nbb = (w >> 1) * 3;

    // A DMA: wave w stages rows w*8..w*8+7 (1 KB, linear dest).  Lane covers
    // row = w*8 + (lane>>3), physical chunk lane&7 holds logical chunk
    // (lane&7)^(row&7) -> source pre-swizzled.
    const int arow = w * 8 + (lane >> 3);
    const int achk = (lane & 7) ^ (lane >> 3);
    const float* asrc = idx + (long)(r0 + arow) * 1024 + achk * 4;

    // FW DMA: 24 segs/phase (seg = nblk*2 + hl); wave w stages segs 3w..3w+2.
    const u16* fsrc[3];
    int fdst[3];
    #pragma unroll
    for (int j = 0; j < 3; ++j) {
        const int seg = w * 3 + j;
        const int nblk = seg >> 1, hl = seg & 1;
        fsrc[j] = (hl ? FWL : FWH) + (long)nblk * 16384 + lane * 8;
        fdst[j] = seg * 512;
    }

#define ABUF(NB) ((float*)(smem[NB]))
#define FBUF(NB) ((u16*)(smem[(NB)] + 8192))

#define ISSUE(PH)                                                             \
    {                                                                         \
        const int nb_ = (PH) & 3;                                             \
        __builtin_amdgcn_global_load_lds((gas_p)(asrc + (PH) * 32),           \
            (las_p)(ABUF(nb_) + w * 256), 16, 0, 0);                          \
        _Pragma("unroll")                                                     \
        for (int j = 0; j < 3; ++j)                                           \
            __builtin_amdgcn_global_load_lds((gas_p)(fsrc[j] + (long)(PH) * 512), \
                (las_p)(FBUF(nb_) + fdst[j]), 16, 0, 0);                      \
    }

#define COMPUTE(PH)                                                           \
    {                                                                         \
        const int nb_ = (PH) & 3;                                             \
        const float* A_ = ABUF(nb_);                                          \
        const u16* F_ = FBUF(nb_);                                            \
        bf16x8 AH[2], AL[2];                                                  \
        _Pragma("unroll")                                                     \
        for (int mi = 0; mi < 2; ++mi) {                                      \
            const int R = m0 + mi * 16 + lr;                                  \
            const int c0 = (quad * 2) ^ (lr & 7);                             \
            const f32x4 x0 = *(const f32x4*)&A_[R * 32 + c0 * 4];             \
            const f32x4 x1 = *(const f32x4*)&A_[R * 32 + (c0 ^ 1) * 4];       \
            split8(x0, x1, &AH[mi], &AL[mi]);                                 \
        }                                                                     \
        _Pragma("unroll")                                                     \
        for (int nf = 0; nf < 3; ++nf) {                                      \
            const int sb = ((nbb + nf) * 2) * 512 + lane * 8;                 \
            const bf16x8 bh = *(const bf16x8*)&F_[sb];                        \
            const bf16x8 bl = *(const bf16x8*)&F_[sb + 512];                  \
            _Pragma("unroll")                                                 \
            for (int mi = 0; mi < 2; ++mi) {                                  \
                f32x4 c = acc[mi][nf];                                        \
                c = MFMA(AH[mi], bh, c);                                      \
                c = MFMA(AL[mi], bh, c);                                      \
                c = MFMA(AH[mi], bl, c);                                      \
                acc[mi][nf] = c;                                              \
            }                                                                 \
        }                                                                     \
    }

#define WAITV(N)                                                              \
    asm volatile("s_waitcnt vmcnt(" #N ")" ::: "memory");                     \
    __builtin_amdgcn_sched_barrier(0);                                        \
    __builtin_amdgcn_s_barrier();

    f32x4 acc[2][3] = {};

    ISSUE(0); ISSUE(1); ISSUE(2);
    WAITV(8)

    for (int ph = 0; ph < 29; ++ph) {
        ISSUE(ph + 3);
        __builtin_amdgcn_sched_barrier(0);
        COMPUTE(ph);
        WAITV(8)
    }
    COMPUTE(29);
    WAITV(4)
    COMPUTE(30);
    WAITV(0)
    COMPUTE(31);

#undef WAITV
#undef COMPUTE
#undef ISSUE
#undef ABUF
#undef FBUF

    #pragma unroll
    for (int mi = 0; mi < 2; ++mi) {
        const int tb = t0 + m0 + mi * 16 + quad * 4;
        const int tblk = (t0 + m0 + mi * 16) >> 4;
        #pragma unroll
        for (int nf = 0; nf < 3; ++nf) {
            const int n = (nbb + nf) * 16 + lr;
            const f32x4 a = acc[mi][nf];
            if (n < 128) {
                u16* Hd = (n < 64) ? FQH : FKH;
                u16* Ld = (n < 64) ? FQL : FKL;
                const int h = n & 63;
                const int kc = h >> 5;
                const int lsub = 16 * ((h & 31) >> 3);
                const long base = ((long)(b * 128 + tblk) * 2 + kc) * 512 + (h & 7);
                #pragma unroll
                for (int r = 0; r < 4; ++r) {
                    const float v = a[r];
                    const u16 hi = f2bf(v);
                    const u16 lo = f2bf(v - bf2f(hi));
                    const long o = base + (long)(quad * 4 + r + lsub) * 8;
                    Hd[o] = hi; Ld[o] = lo;
                }
            } else {
                const int h = n - 128;
                const int hblk = h >> 4;
                #pragma unroll
                for (int r = 0; r < 4; ++r) {
                    const int t = tb + r;
                    const long o = ((long)(b * 4 + hblk) * 64 + (t >> 5)) * 512
                                 + (long)(16 * ((t & 31) >> 3) + (h & 15)) * 8 + (t & 7);
                    VF[o] = f2bf(a[r]);
                }
            }
        }
    }
}

// ---------------------------------------------------------------------------
// stats: D_s = sum_{t>=s} exp(q_t.k_s)  AND stores P = exp (masked, bf16)
// into A-fragment layout PF[b][tblk][kc=s/32][lane][8].  K B-frags hoisted,
// Q A-frags per-jt (all fragment-coalesced 1KB loads).  No staging LDS.
// Grid (144, B): s-tile i, t-chunk c (<=4 t-tiles); atomicAdd partials.
// ---------------------------------------------------------------------------
__global__ __launch_bounds__(256, 4) void stats_kernel(
    const u16* __restrict__ FQH, const u16* __restrict__ FQL,
    const u16* __restrict__ FKH, const u16* __restrict__ FKL,
    u16* __restrict__ PF, float* __restrict__ D)
{
    __shared__ float red[4][64];
    const int tid = threadIdx.x;
    const int w = tid >> 6, lr = tid & 15, quad = (tid >> 4) & 3;
    const int lane = tid & 63;
    const int b = blockIdx.y;
    int x = blockIdx.x, i = 0;
    for (;;) { const int nc = (35 - i) >> 2; if (x < nc) break; x -= nc; ++i; }
    const int s0 = i * 64;
    const int jt0 = i + 4 * x, jt1 = min(jt0 + 4, 32);

    bf16x8 BH[4][2], BL[4][2];
    #pragma unroll
    for (int nf = 0; nf < 4; ++nf) {
        const long kb = ((long)(b * 128 + i * 4 + nf) * 2) * 512 + lane * 8;
        BH[nf][0] = *(const bf16x8*)&FKH[kb];
        BH[nf][1] = *(const bf16x8*)&FKH[kb + 512];
        BL[nf][0] = *(const bf16x8*)&FKL[kb];
        BL[nf][1] = *(const bf16x8*)&FKL[kb + 512];
    }

    float dsum[4] = {0.f, 0.f, 0.f, 0.f};
    for (int jt = jt0; jt < jt1; ++jt) {
        const long qb = ((long)(b * 128 + jt * 4 + w) * 2) * 512 + lane * 8;
        const bf16x8 ah0 = *(const bf16x8*)&FQH[qb];
        const bf16x8 ah1 = *(const bf16x8*)&FQH[qb + 512];
        const bf16x8 al0 = *(const bf16x8*)&FQL[qb];
        const bf16x8 al1 = *(const bf16x8*)&FQL[qb + 512];
        const bool diag = (jt == i);
        #pragma unroll
        for (int nf = 0; nf < 4; ++nf) {
            f32x4 cc = {};
            cc = MFMA(ah0, BH[nf][0], cc);
            cc = MFMA(al0, BH[nf][0], cc);
            cc = MFMA(ah0, BL[nf][0], cc);
            cc = MFMA(ah1, BH[nf][1], cc);
            cc = MFMA(al1, BH[nf][1], cc);
            cc = MFMA(ah1, BL[nf][1], cc);

            // P store base: t = jt*64 + w*16 + quad*4 + r, s = i*64 + nf*16 + lr
            const long pbase = ((long)(b * 128 + jt * 4 + w) * 64 + i * 2 + (nf >> 1)) * 512
                             + (long)(((nf & 1) * 2 + (lr >> 3)) * 16) * 8 + (lr & 7);
            const int sl = nf * 16 + lr;
            #pragma unroll
            for (int r = 0; r < 4; ++r) {
                float ev = __expf(cc[r]);
                if (diag && (w * 16 + quad * 4 + r < sl)) ev = 0.f;
                dsum[nf] += ev;
                PF[pbase + (long)(quad * 4 + r) * 8] = f2bf(ev);
            }
        }
    }

    #pragma unroll
    for (int nf = 0; nf < 4; ++nf) {
        dsum[nf] += __shfl_xor(dsum[nf], 16);
        dsum[nf] += __shfl_xor(dsum[nf], 32);
    }
    if (quad == 0) {
        #pragma unroll
        for (int nf = 0; nf < 4; ++nf) red[w][nf * 16 + lr] = dsum[nf];
    }
    __syncthreads();
    if (tid < 64)
        atomicAdd(&D[b * 2048 + s0 + tid],
                  red[0][tid] + red[1][tid] + red[2][tid] + red[3][tid]);
}

// ---------------------------------------------------------------------------
// vscale: VF (B-fragment layout) *= 1/D[s].  Entry (b,hblk,kc,lane,j) has
// s = kc*32 + (lane>>4)*8 + j  (j consecutive in s).
// ---------------------------------------------------------------------------
__global__ __launch_bounds__(256) void vscale_kernel(
    u16* __restrict__ VF, const float* __restrict__ D)
{
    const int g = blockIdx.x * 256 + threadIdx.x;   // 131072 threads x 8 u16
    const long e = (long)g * 8;
    const int lane = (int)((e >> 3) & 63);
    const int kc   = (int)((e >> 9) & 63);
    const int b    = (int)(e >> 17);
    const int s = kc * 32 + (lane >> 4) * 8;
    const float4 d0 = *(const float4*)&D[b * 2048 + s];
    const float4 d1 = *(const float4*)&D[b * 2048 + s + 4];
    const float dv[8] = {d0.x, d0.y, d0.z, d0.w, d1.x, d1.y, d1.z, d1.w};
    bf16x8 vv = *(bf16x8*)&VF[e];
    bf16x8 ov;
    #pragma unroll
    for (int j = 0; j < 8; ++j)
        ov[j] = (short)f2bf(bf2f((u16)vv[j]) / dv[j]);
    *(bf16x8*)&VF[e] = ov;
}

// ---------------------------------------------------------------------------
// out: pure streaming PV GEMM.  out[t][h] = sum_{s<=t} P[t][s] * Vtilde[s][h].
// Per s-tile: 2 P A-frag loads + 8 V B-frag loads + 8 MFMA.  No LDS, no
// barriers, no exp.  Grid (80, B): t-tile i, s-chunk c (<=8 s-tiles).
// ---------------------------------------------------------------------------
__global__ __launch_bounds__(256, 4) void out_kernel(
    const u16* __restrict__ PF, const u16* __restrict__ VF,
    float* __restrict__ out)
{
    const int tid = threadIdx.x;
    const int w = tid >> 6, lr = tid & 15, quad = (tid >> 4) & 3;
    const int lane = tid & 63;
    const int b = blockIdx.y;
    int x = blockIdx.x, i = 0;
    for (;;) { const int nc = (i + 8) >> 3; if (x < nc) break; x -= nc; ++i; }
    const int t0 = i * 64;
    const int js0 = 8 * x, js1 = min(8 * x + 8, i + 1);
    const int tblk = i * 4 + w;

    f32x4 oacc[4] = {};
    for (int js = js0; js < js1; ++js) {
        const long pb = ((long)(b * 128 + tblk) * 64 + 2 * js) * 512 + lane * 8;
        const bf16x8 a0 = *(const bf16x8*)&PF[pb];
        const bf16x8 a1 = *(const bf16x8*)&PF[pb + 512];
        #pragma unroll
        for (int nf = 0; nf < 4; ++nf) {
            const long vb = ((long)(b * 4 + nf) * 64 + 2 * js) * 512 + lane * 8;
            const bf16x8 v0 = *(const bf16x8*)&VF[vb];
            const bf16x8 v1 = *(const bf16x8*)&VF[vb + 512];
            oacc[nf] = MFMA(a0, v0, oacc[nf]);
            oacc[nf] = MFMA(a1, v1, oacc[nf]);
        }
    }

    const bool single = (i < 8);   // one chunk covers the whole row
    #pragma unroll
    for (int nf = 0; nf < 4; ++nf) {
        const int h = nf * 16 + lr;
        #pragma unroll
        for (int r = 0; r < 4; ++r) {
            const int t = t0 + w * 16 + quad * 4 + r;
            const long o = (long)(b * 2048 + t) * 64 + h;
            if (single) out[o] = oacc[nf][r];
            else        atomicAdd(&out[o], oacc[nf][r]);
        }
    }
}

extern "C" void kernel_launch(void* const* d_in, const int* in_sizes, int n_in,
                              void* d_out, int out_size, void* d_ws, size_t ws_size,
                              hipStream_t stream)
{
    const float* idx = (const float*)d_in[0];
    const float* Wk  = (const float*)d_in[1];
    const float* Wq  = (const float*)d_in[2];
    const float* Wv  = (const float*)d_in[3];
    char* ws = (char*)d_ws;
    float* out = (float*)d_out;

    u16* FWH = (u16*)(ws + WH_OFF);  u16* FWL = (u16*)(ws + WL_OFF);
    u16* FQH = (u16*)(ws + FQH_OFF); u16* FQL = (u16*)(ws + FQL_OFF);
    u16* FKH = (u16*)(ws + FKH_OFF); u16* FKL = (u16*)(ws + FKL_OFF);
    u16* VF  = (u16*)(ws + VF_OFF);
    float* Dp = (float*)(ws + DD_OFF);
    u16* PF  = (u16*)(ws + PF_OFF);

    hipMemsetAsync(out, 0, (size_t)8 * 2048 * 64 * sizeof(float), stream);
    hipMemsetAsync(Dp, 0, (size_t)8 * 2048 * sizeof(float), stream);

    wsplit_kernel<<<192, 128, 0, stream>>>(Wk, Wq, Wv, FWH, FWL);
    qkv_kernel<<<256, 512, 0, stream>>>(idx, FWH, FWL, FQH, FQL, FKH, FKL, VF);
    stats_kernel<<<dim3(144, 8), 256, 0, stream>>>(FQH, FQL, FKH, FKL, PF, Dp);
    vscale_kernel<<<512, 256, 0, stream>>>(VF, Dp);
    out_kernel<<<dim3(80, 8), 256, 0, stream>>>(PF, VF, out);
}

// Round 7
// 153.762 us; speedup vs baseline: 1.1157x; 1.0526x over previous
//
#include <hip/hip_runtime.h>

// B=8, T=2048, C=1024, H=64.  Reference: softmax over QUERY axis (dim=1),
// no 1/sqrt(d) scale.  out[t,h] = sum_{s<=t} exp(q_t.k_s)/D_s * v[s,h],
// D_s = sum_{t>=s} exp(q_t.k_s).
//
// qkv GEMM: 2-term split (exact-A x bf16-W): A = AH+AL (trunc split, ~fp32),
// W = RNE bf16.  Q/K stored hi+lo for stats' 3-term QK dots; V, P plain bf16.
// Round-19: counted-vmcnt DMA pipeline moved qkv 42.5 -> ~40 (out of top-5).
// Round-20: cut the WORK: 3-term -> 2-term (MFMA 1.18M -> 786K, FW bytes
// halve — FWL never read).  Phase K=64, 3 stages (120 KB LDS), 5 DMA/wave/
// phase uniform, boundary s_waitcnt vmcnt(5) + bare s_barrier, 16 barriers.

typedef __attribute__((ext_vector_type(8))) short bf16x8;
typedef __attribute__((ext_vector_type(4))) float f32x4;
typedef unsigned short u16;

#define MFMA(a, b, c) __builtin_amdgcn_mfma_f32_16x16x32_bf16((a), (b), (c), 0, 0, 0)

__device__ __forceinline__ u16 f2bf(float x) {           // RNE fp32 -> bf16
    unsigned u = __float_as_uint(x);
    u += 0x7fff + ((u >> 16) & 1);
    return (u16)(u >> 16);
}
__device__ __forceinline__ float bf2f(u16 h) {
    return __uint_as_float(((unsigned)h) << 16);
}

// trunc-split 8 fp32 -> hi bf16x8 + lo bf16x8 (exact residual).  ~3 VALU/flt.
__device__ __forceinline__ void split8(const f32x4 x0, const f32x4 x1,
                                       bf16x8* hv, bf16x8* lv)
{
    const float f[8] = {x0[0], x0[1], x0[2], x0[3], x1[0], x1[1], x1[2], x1[3]};
    union { unsigned u[4]; bf16x8 v; } H, L;
    #pragma unroll
    for (int j = 0; j < 4; ++j) {
        const unsigned u0 = __float_as_uint(f[2 * j]);
        const unsigned u1 = __float_as_uint(f[2 * j + 1]);
        H.u[j] = __builtin_amdgcn_perm(u1, u0, 0x07060302);   // top16 of each
        const float l0 = f[2 * j]     - __uint_as_float(u0 & 0xffff0000u);
        const float l1 = f[2 * j + 1] - __uint_as_float(u1 & 0xffff0000u);
        L.u[j] = __builtin_amdgcn_perm(__float_as_uint(l1), __float_as_uint(l0),
                                       0x07060302);
    }
    *hv = H.v;
    *lv = L.v;
}

typedef const __attribute__((address_space(1))) void* gas_p;
typedef __attribute__((address_space(3))) void* las_p;

// ws byte offsets
#define WH_OFF  0u
#define WL_OFF  (WH_OFF + 192u*1024u*2u)
#define FQH_OFF (WL_OFF + 192u*1024u*2u)
#define FQL_OFF (FQH_OFF + 2u*1024u*1024u)
#define FKH_OFF (FQL_OFF + 2u*1024u*1024u)
#define FKL_OFF (FKH_OFF + 2u*1024u*1024u)
#define VF_OFF  (FKL_OFF + 2u*1024u*1024u)
#define DD_OFF  (VF_OFF + 2u*1024u*1024u)          // fp32 [B][T] = 64 KB
#define PF_OFF  (DD_OFF + 8u*2048u*4u)             // bf16, 67 MB

// ---------------------------------------------------------------------------
// W -> fragment-coalesced bf16 (RNE).  Chunk kc (32 K-elems) of col-block
// nblk lives at nblk*16384 + kc*512 u16.  (No lo-part: 2-term scheme.)
// ---------------------------------------------------------------------------
__global__ __launch_bounds__(128) void wsplit_kernel(
    const float* __restrict__ Wk, const float* __restrict__ Wq,
    const float* __restrict__ Wv, u16* __restrict__ FWH)
{
    const int n = blockIdx.x;                 // 0..191
    const int nblk = n >> 4, lr = n & 15;
    const float* src = (n < 64) ? (Wq + (long)n * 1024)
                     : (n < 128) ? (Wk + (long)(n - 64) * 1024)
                                 : (Wv + (long)(n - 128) * 1024);
    const int f = threadIdx.x;                // 0..127 fragment id
    const int kc = f >> 2, q = f & 3;
    const float4 f0 = *(const float4*)&src[kc * 32 + q * 8];
    const float4 f1 = *(const float4*)&src[kc * 32 + q * 8 + 4];
    const float vs[8] = {f0.x, f0.y, f0.z, f0.w, f1.x, f1.y, f1.z, f1.w};
    bf16x8 hv;
    #pragma unroll
    for (int j = 0; j < 8; ++j) hv[j] = (short)f2bf(vs[j]);
    const long o = ((long)(nblk * 32 + kc) * 64 + q * 16 + lr) * 8;
    *(bf16x8*)&FWH[o] = hv;
}

// ---------------------------------------------------------------------------
// qkv.  M-tile 64, 512 thr = 8 waves (2m x 4n), grid 256.  Counted-vmcnt DMA
// pipeline: phase = K=64; per wave per phase 5 global_load_lds (2 A fp32 segs
// + 3 FWH segs, uniform); 3 stages x 40 KB = 120 KB LDS; lookahead 2.
// Boundary s_waitcnt vmcnt(5) (tail 0) + bare s_barrier.  A source chunk-
// swizzled (^row&7); consumer split8 -> AH/AL; 2 MFMA per (mi,nf,kc).
// Epilogue writes Q/K hi+lo and V bf16 fragment layouts (unchanged).
// ---------------------------------------------------------------------------
__global__ __launch_bounds__(512, 2) void qkv_kernel(
    const float* __restrict__ idx, const u16* __restrict__ FWH,
    u16* __restrict__ FQH, u16* __restrict__ FQL,
    u16* __restrict__ FKH, u16* __restrict__ FKL, u16* __restrict__ VF)
{
    __shared__ __align__(16) char smem[3][40960];   // A 16KB + FWH 24KB
    const int tid = threadIdx.x;
    const int w = tid >> 6, lr = tid & 15, quad = (tid >> 4) & 3;
    const int lane = tid & 63;
    const int r0 = blockIdx.x * 64;
    const int b = r0 >> 11, t0 = r0 & 2047;
    const int m0 = (w & 1) * 32;
    const int nbb = (w >> 1) * 3;

    // A DMA: 16 segs/phase (1 KB = 4 rows x 64 cols); wave w -> segs 2w,2w+1.
    // Lane: row = 4*seg + (lane>>4), phys chunk lane&15 holds logical
    // (lane&15)^(row&7) -> source pre-swizzled, LDS dest linear.
    const float* asrc[2];
    int adst[2];
    #pragma unroll
    for (int j = 0; j < 2; ++j) {
        const int s = w * 2 + j;
        const int row = s * 4 + (lane >> 4);
        const int lc = (lane & 15) ^ (row & 7);
        asrc[j] = idx + (long)(r0 + row) * 1024 + lc * 4;
        adst[j] = s * 1024;                    // byte offset in stage
    }
    // FWH DMA: 24 segs/phase (seg = nblk*2 + kcl); wave w -> segs 3w..3w+2.
    const u16* fsrc[3];
    int fdst[3];
    #pragma unroll
    for (int j = 0; j < 3; ++j) {
        const int seg = w * 3 + j;
        const int nblk = seg >> 1, kcl = seg & 1;
        fsrc[j] = FWH + (long)nblk * 16384 + kcl * 512 + lane * 8;
        fdst[j] = 16384 + seg * 1024;          // byte offset in stage
    }

#define ISSUE(PH)                                                             \
    {                                                                         \
        const int nb_ = (PH) % 3;                                             \
        _Pragma("unroll")                                                     \
        for (int j = 0; j < 2; ++j)                                           \
            __builtin_amdgcn_global_load_lds((gas_p)(asrc[j] + (PH) * 64),    \
                (las_p)(smem[nb_] + adst[j]), 16, 0, 0);                      \
        _Pragma("unroll")                                                     \
        for (int j = 0; j < 3; ++j)                                           \
            __builtin_amdgcn_global_load_lds((gas_p)(fsrc[j] + (long)(PH) * 1024), \
                (las_p)(smem[nb_] + fdst[j]), 16, 0, 0);                      \
    }

#define COMPUTE(PH)                                                           \
    {                                                                         \
        const int nb_ = (PH) % 3;                                             \
        const float* A_ = (const float*)smem[nb_];                            \
        const u16* F_ = (const u16*)(smem[nb_] + 16384);                      \
        _Pragma("unroll")                                                     \
        for (int kc = 0; kc < 2; ++kc) {                                      \
            bf16x8 AH[2], AL[2];                                              \
            _Pragma("unroll")                                                 \
            for (int mi = 0; mi < 2; ++mi) {                                  \
                const int R = m0 + mi * 16 + lr;                              \
                const int c0 = (kc * 8 + quad * 2) ^ (lr & 7);                \
                const f32x4 x0 = *(const f32x4*)&A_[R * 64 + c0 * 4];         \
                const f32x4 x1 = *(const f32x4*)&A_[R * 64 + (c0 ^ 1) * 4];   \
                split8(x0, x1, &AH[mi], &AL[mi]);                             \
            }                                                                 \
            _Pragma("unroll")                                                 \
            for (int nf = 0; nf < 3; ++nf) {                                  \
                const int sb = (((nbb + nf) * 2 + kc)) * 512 + lane * 8;      \
                const bf16x8 bh = *(const bf16x8*)&F_[sb];                    \
                _Pragma("unroll")                                             \
                for (int mi = 0; mi < 2; ++mi) {                              \
                    f32x4 c = acc[mi][nf];                                    \
                    c = MFMA(AH[mi], bh, c);                                  \
                    c = MFMA(AL[mi], bh, c);                                  \
                    acc[mi][nf] = c;                                          \
                }                                                             \
            }                                                                 \
        }                                                                     \
    }

#define WAITV(N)                                                              \
    asm volatile("s_waitcnt vmcnt(" #N ")" ::: "memory");                     \
    __builtin_amdgcn_sched_barrier(0);                                        \
    __builtin_amdgcn_s_barrier();

    f32x4 acc[2][3] = {};

    ISSUE(0); ISSUE(1);
    WAITV(5)

    for (int ph = 0; ph < 14; ++ph) {
        ISSUE(ph + 2);
        __builtin_amdgcn_sched_barrier(0);
        COMPUTE(ph);
        WAITV(5)
    }
    COMPUTE(14);
    WAITV(0)
    COMPUTE(15);

#undef WAITV
#undef COMPUTE
#undef ISSUE

    #pragma unroll
    for (int mi = 0; mi < 2; ++mi) {
        const int tb = t0 + m0 + mi * 16 + quad * 4;
        const int tblk = (t0 + m0 + mi * 16) >> 4;
        #pragma unroll
        for (int nf = 0; nf < 3; ++nf) {
            const int n = (nbb + nf) * 16 + lr;
            const f32x4 a = acc[mi][nf];
            if (n < 128) {
                u16* Hd = (n < 64) ? FQH : FKH;
                u16* Ld = (n < 64) ? FQL : FKL;
                const int h = n & 63;
                const int kc = h >> 5;
                const int lsub = 16 * ((h & 31) >> 3);
                const long base = ((long)(b * 128 + tblk) * 2 + kc) * 512 + (h & 7);
                #pragma unroll
                for (int r = 0; r < 4; ++r) {
                    const float v = a[r];
                    const u16 hi = f2bf(v);
                    const u16 lo = f2bf(v - bf2f(hi));
                    const long o = base + (long)(quad * 4 + r + lsub) * 8;
                    Hd[o] = hi; Ld[o] = lo;
                }
            } else {
                const int h = n - 128;
                const int hblk = h >> 4;
                #pragma unroll
                for (int r = 0; r < 4; ++r) {
                    const int t = tb + r;
                    const long o = ((long)(b * 4 + hblk) * 64 + (t >> 5)) * 512
                                 + (long)(16 * ((t & 31) >> 3) + (h & 15)) * 8 + (t & 7);
                    VF[o] = f2bf(a[r]);
                }
            }
        }
    }
}

// ---------------------------------------------------------------------------
// stats: D_s = sum_{t>=s} exp(q_t.k_s)  AND stores P = exp (masked, bf16)
// into A-fragment layout PF[b][tblk][kc=s/32][lane][8].  K B-frags hoisted,
// Q A-frags per-jt (all fragment-coalesced 1KB loads).  No staging LDS.
// Grid (144, B): s-tile i, t-chunk c (<=4 t-tiles); atomicAdd partials.
// ---------------------------------------------------------------------------
__global__ __launch_bounds__(256, 4) void stats_kernel(
    const u16* __restrict__ FQH, const u16* __restrict__ FQL,
    const u16* __restrict__ FKH, const u16* __restrict__ FKL,
    u16* __restrict__ PF, float* __restrict__ D)
{
    __shared__ float red[4][64];
    const int tid = threadIdx.x;
    const int w = tid >> 6, lr = tid & 15, quad = (tid >> 4) & 3;
    const int lane = tid & 63;
    const int b = blockIdx.y;
    int x = blockIdx.x, i = 0;
    for (;;) { const int nc = (35 - i) >> 2; if (x < nc) break; x -= nc; ++i; }
    const int s0 = i * 64;
    const int jt0 = i + 4 * x, jt1 = min(jt0 + 4, 32);

    bf16x8 BH[4][2], BL[4][2];
    #pragma unroll
    for (int nf = 0; nf < 4; ++nf) {
        const long kb = ((long)(b * 128 + i * 4 + nf) * 2) * 512 + lane * 8;
        BH[nf][0] = *(const bf16x8*)&FKH[kb];
        BH[nf][1] = *(const bf16x8*)&FKH[kb + 512];
        BL[nf][0] = *(const bf16x8*)&FKL[kb];
        BL[nf][1] = *(const bf16x8*)&FKL[kb + 512];
    }

    float dsum[4] = {0.f, 0.f, 0.f, 0.f};
    for (int jt = jt0; jt < jt1; ++jt) {
        const long qb = ((long)(b * 128 + jt * 4 + w) * 2) * 512 + lane * 8;
        const bf16x8 ah0 = *(const bf16x8*)&FQH[qb];
        const bf16x8 ah1 = *(const bf16x8*)&FQH[qb + 512];
        const bf16x8 al0 = *(const bf16x8*)&FQL[qb];
        const bf16x8 al1 = *(const bf16x8*)&FQL[qb + 512];
        const bool diag = (jt == i);
        #pragma unroll
        for (int nf = 0; nf < 4; ++nf) {
            f32x4 cc = {};
            cc = MFMA(ah0, BH[nf][0], cc);
            cc = MFMA(al0, BH[nf][0], cc);
            cc = MFMA(ah0, BL[nf][0], cc);
            cc = MFMA(ah1, BH[nf][1], cc);
            cc = MFMA(al1, BH[nf][1], cc);
            cc = MFMA(ah1, BL[nf][1], cc);

            // P store base: t = jt*64 + w*16 + quad*4 + r, s = i*64 + nf*16 + lr
            const long pbase = ((long)(b * 128 + jt * 4 + w) * 64 + i * 2 + (nf >> 1)) * 512
                             + (long)(((nf & 1) * 2 + (lr >> 3)) * 16) * 8 + (lr & 7);
            const int sl = nf * 16 + lr;
            #pragma unroll
            for (int r = 0; r < 4; ++r) {
                float ev = __expf(cc[r]);
                if (diag && (w * 16 + quad * 4 + r < sl)) ev = 0.f;
                dsum[nf] += ev;
                PF[pbase + (long)(quad * 4 + r) * 8] = f2bf(ev);
            }
        }
    }

    #pragma unroll
    for (int nf = 0; nf < 4; ++nf) {
        dsum[nf] += __shfl_xor(dsum[nf], 16);
        dsum[nf] += __shfl_xor(dsum[nf], 32);
    }
    if (quad == 0) {
        #pragma unroll
        for (int nf = 0; nf < 4; ++nf) red[w][nf * 16 + lr] = dsum[nf];
    }
    __syncthreads();
    if (tid < 64)
        atomicAdd(&D[b * 2048 + s0 + tid],
                  red[0][tid] + red[1][tid] + red[2][tid] + red[3][tid]);
}

// ---------------------------------------------------------------------------
// vscale: VF (B-fragment layout) *= 1/D[s].  Entry (b,hblk,kc,lane,j) has
// s = kc*32 + (lane>>4)*8 + j  (j consecutive in s).
// ---------------------------------------------------------------------------
__global__ __launch_bounds__(256) void vscale_kernel(
    u16* __restrict__ VF, const float* __restrict__ D)
{
    const int g = blockIdx.x * 256 + threadIdx.x;   // 131072 threads x 8 u16
    const long e = (long)g * 8;
    const int lane = (int)((e >> 3) & 63);
    const int kc   = (int)((e >> 9) & 63);
    const int b    = (int)(e >> 17);
    const int s = kc * 32 + (lane >> 4) * 8;
    const float4 d0 = *(const float4*)&D[b * 2048 + s];
    const float4 d1 = *(const float4*)&D[b * 2048 + s + 4];
    const float dv[8] = {d0.x, d0.y, d0.z, d0.w, d1.x, d1.y, d1.z, d1.w};
    bf16x8 vv = *(bf16x8*)&VF[e];
    bf16x8 ov;
    #pragma unroll
    for (int j = 0; j < 8; ++j)
        ov[j] = (short)f2bf(bf2f((u16)vv[j]) / dv[j]);
    *(bf16x8*)&VF[e] = ov;
}

// ---------------------------------------------------------------------------
// out: pure streaming PV GEMM.  out[t][h] = sum_{s<=t} P[t][s] * Vtilde[s][h].
// Per s-tile: 2 P A-frag loads + 8 V B-frag loads + 8 MFMA.  No LDS, no
// barriers, no exp.  Grid (80, B): t-tile i, s-chunk c (<=8 s-tiles).
// ---------------------------------------------------------------------------
__global__ __launch_bounds__(256, 4) void out_kernel(
    const u16* __restrict__ PF, const u16* __restrict__ VF,
    float* __restrict__ out)
{
    const int tid = threadIdx.x;
    const int w = tid >> 6, lr = tid & 15, quad = (tid >> 4) & 3;
    const int lane = tid & 63;
    const int b = blockIdx.y;
    int x = blockIdx.x, i = 0;
    for (;;) { const int nc = (i + 8) >> 3; if (x < nc) break; x -= nc; ++i; }
    const int t0 = i * 64;
    const int js0 = 8 * x, js1 = min(8 * x + 8, i + 1);
    const int tblk = i * 4 + w;

    f32x4 oacc[4] = {};
    for (int js = js0; js < js1; ++js) {
        const long pb = ((long)(b * 128 + tblk) * 64 + 2 * js) * 512 + lane * 8;
        const bf16x8 a0 = *(const bf16x8*)&PF[pb];
        const bf16x8 a1 = *(const bf16x8*)&PF[pb + 512];
        #pragma unroll
        for (int nf = 0; nf < 4; ++nf) {
            const long vb = ((long)(b * 4 + nf) * 64 + 2 * js) * 512 + lane * 8;
            const bf16x8 v0 = *(const bf16x8*)&VF[vb];
            const bf16x8 v1 = *(const bf16x8*)&VF[vb + 512];
            oacc[nf] = MFMA(a0, v0, oacc[nf]);
            oacc[nf] = MFMA(a1, v1, oacc[nf]);
        }
    }

    const bool single = (i < 8);   // one chunk covers the whole row
    #pragma unroll
    for (int nf = 0; nf < 4; ++nf) {
        const int h = nf * 16 + lr;
        #pragma unroll
        for (int r = 0; r < 4; ++r) {
            const int t = t0 + w * 16 + quad * 4 + r;
            const long o = (long)(b * 2048 + t) * 64 + h;
            if (single) out[o] = oacc[nf][r];
            else        atomicAdd(&out[o], oacc[nf][r]);
        }
    }
}

extern "C" void kernel_launch(void* const* d_in, const int* in_sizes, int n_in,
                              void* d_out, int out_size, void* d_ws, size_t ws_size,
                              hipStream_t stream)
{
    const float* idx = (const float*)d_in[0];
    const float* Wk  = (const float*)d_in[1];
    const float* Wq  = (const float*)d_in[2];
    const float* Wv  = (const float*)d_in[3];
    char* ws = (char*)d_ws;
    float* out = (float*)d_out;

    u16* FWH = (u16*)(ws + WH_OFF);
    u16* FQH = (u16*)(ws + FQH_OFF); u16* FQL = (u16*)(ws + FQL_OFF);
    u16* FKH = (u16*)(ws + FKH_OFF); u16* FKL = (u16*)(ws + FKL_OFF);
    u16* VF  = (u16*)(ws + VF_OFF);
    float* Dp = (float*)(ws + DD_OFF);
    u16* PF  = (u16*)(ws + PF_OFF);

    hipMemsetAsync(out, 0, (size_t)8 * 2048 * 64 * sizeof(float), stream);
    hipMemsetAsync(Dp, 0, (size_t)8 * 2048 * sizeof(float), stream);

    wsplit_kernel<<<192, 128, 0, stream>>>(Wk, Wq, Wv, FWH);
    qkv_kernel<<<256, 512, 0, stream>>>(idx, FWH, FQH, FQL, FKH, FKL, VF);
    stats_kernel<<<dim3(144, 8), 256, 0, stream>>>(FQH, FQL, FKH, FKL, PF, Dp);
    vscale_kernel<<<512, 256, 0, stream>>>(VF, Dp);
    out_kernel<<<dim3(80, 8), 256, 0, stream>>>(PF, VF, out);
}

// Round 8
// 149.759 us; speedup vs baseline: 1.1455x; 1.0267x over previous
//
#include <hip/hip_runtime.h>

// B=8, T=2048, C=1024, H=64.  Reference: softmax over QUERY axis (dim=1),
// no 1/sqrt(d) scale.  out[t,h] = sum_{s<=t} exp(q_t.k_s)/D_s * v[s,h],
// D_s = sum_{t>=s} exp(q_t.k_s).
//
// qkv GEMM: 2-term split (exact-A x bf16-W).  Q/K stored hi+lo for stats'
// 3-term QK dots; V, P plain bf16.  qkv: counted-vmcnt DMA pipeline (r20).
// Round-21: stats P-store descatter.  Old: 16 scalar 2B global stores per
// thread per jt (18.9M VMEM ops) because MFMA C-layout (fixed-t, strided-s)
// mismatches the A-frag P layout.  New: swap QK MFMA operands (MFMA(K,Q) ->
// C row=s col=t: thread holds 4 CONSECUTIVE s at fixed t), pack quartets into
// 8B LDS writes into a swizzled 64x64 tile ((s>>3)^(t&7)), barrier, read back
// as exact A-fragments (ds_read_b128) -> 2 coalesced 16B global stores.

typedef __attribute__((ext_vector_type(8))) short bf16x8;
typedef __attribute__((ext_vector_type(4))) float f32x4;
typedef unsigned short u16;

#define MFMA(a, b, c) __builtin_amdgcn_mfma_f32_16x16x32_bf16((a), (b), (c), 0, 0, 0)

__device__ __forceinline__ u16 f2bf(float x) {           // RNE fp32 -> bf16
    unsigned u = __float_as_uint(x);
    u += 0x7fff + ((u >> 16) & 1);
    return (u16)(u >> 16);
}
__device__ __forceinline__ float bf2f(u16 h) {
    return __uint_as_float(((unsigned)h) << 16);
}

// trunc-split 8 fp32 -> hi bf16x8 + lo bf16x8 (exact residual).  ~3 VALU/flt.
__device__ __forceinline__ void split8(const f32x4 x0, const f32x4 x1,
                                       bf16x8* hv, bf16x8* lv)
{
    const float f[8] = {x0[0], x0[1], x0[2], x0[3], x1[0], x1[1], x1[2], x1[3]};
    union { unsigned u[4]; bf16x8 v; } H, L;
    #pragma unroll
    for (int j = 0; j < 4; ++j) {
        const unsigned u0 = __float_as_uint(f[2 * j]);
        const unsigned u1 = __float_as_uint(f[2 * j + 1]);
        H.u[j] = __builtin_amdgcn_perm(u1, u0, 0x07060302);   // top16 of each
        const float l0 = f[2 * j]     - __uint_as_float(u0 & 0xffff0000u);
        const float l1 = f[2 * j + 1] - __uint_as_float(u1 & 0xffff0000u);
        L.u[j] = __builtin_amdgcn_perm(__float_as_uint(l1), __float_as_uint(l0),
                                       0x07060302);
    }
    *hv = H.v;
    *lv = L.v;
}

typedef const __attribute__((address_space(1))) void* gas_p;
typedef __attribute__((address_space(3))) void* las_p;

// ws byte offsets
#define WH_OFF  0u
#define WL_OFF  (WH_OFF + 192u*1024u*2u)
#define FQH_OFF (WL_OFF + 192u*1024u*2u)
#define FQL_OFF (FQH_OFF + 2u*1024u*1024u)
#define FKH_OFF (FQL_OFF + 2u*1024u*1024u)
#define FKL_OFF (FKH_OFF + 2u*1024u*1024u)
#define VF_OFF  (FKL_OFF + 2u*1024u*1024u)
#define DD_OFF  (VF_OFF + 2u*1024u*1024u)          // fp32 [B][T] = 64 KB
#define PF_OFF  (DD_OFF + 8u*2048u*4u)             // bf16, 67 MB

// ---------------------------------------------------------------------------
// W -> fragment-coalesced bf16 (RNE).  Chunk kc (32 K-elems) of col-block
// nblk lives at nblk*16384 + kc*512 u16.
// ---------------------------------------------------------------------------
__global__ __launch_bounds__(128) void wsplit_kernel(
    const float* __restrict__ Wk, const float* __restrict__ Wq,
    const float* __restrict__ Wv, u16* __restrict__ FWH)
{
    const int n = blockIdx.x;                 // 0..191
    const int nblk = n >> 4, lr = n & 15;
    const float* src = (n < 64) ? (Wq + (long)n * 1024)
                     : (n < 128) ? (Wk + (long)(n - 64) * 1024)
                                 : (Wv + (long)(n - 128) * 1024);
    const int f = threadIdx.x;                // 0..127 fragment id
    const int kc = f >> 2, q = f & 3;
    const float4 f0 = *(const float4*)&src[kc * 32 + q * 8];
    const float4 f1 = *(const float4*)&src[kc * 32 + q * 8 + 4];
    const float vs[8] = {f0.x, f0.y, f0.z, f0.w, f1.x, f1.y, f1.z, f1.w};
    bf16x8 hv;
    #pragma unroll
    for (int j = 0; j < 8; ++j) hv[j] = (short)f2bf(vs[j]);
    const long o = ((long)(nblk * 32 + kc) * 64 + q * 16 + lr) * 8;
    *(bf16x8*)&FWH[o] = hv;
}

// ---------------------------------------------------------------------------
// qkv (r20 verbatim).  Counted-vmcnt DMA pipeline, 2-term split, phase K=64,
// 3 stages x 40 KB LDS, 5 DMA/wave/phase, boundary vmcnt(5) + bare s_barrier.
// ---------------------------------------------------------------------------
__global__ __launch_bounds__(512, 2) void qkv_kernel(
    const float* __restrict__ idx, const u16* __restrict__ FWH,
    u16* __restrict__ FQH, u16* __restrict__ FQL,
    u16* __restrict__ FKH, u16* __restrict__ FKL, u16* __restrict__ VF)
{
    __shared__ __align__(16) char smem[3][40960];   // A 16KB + FWH 24KB
    const int tid = threadIdx.x;
    const int w = tid >> 6, lr = tid & 15, quad = (tid >> 4) & 3;
    const int lane = tid & 63;
    const int r0 = blockIdx.x * 64;
    const int b = r0 >> 11, t0 = r0 & 2047;
    const int m0 = (w & 1) * 32;
    const int nbb = (w >> 1) * 3;

    const float* asrc[2];
    int adst[2];
    #pragma unroll
    for (int j = 0; j < 2; ++j) {
        const int s = w * 2 + j;
        const int row = s * 4 + (lane >> 4);
        const int lc = (lane & 15) ^ (row & 7);
        asrc[j] = idx + (long)(r0 + row) * 1024 + lc * 4;
        adst[j] = s * 1024;
    }
    const u16* fsrc[3];
    int fdst[3];
    #pragma unroll
    for (int j = 0; j < 3; ++j) {
        const int seg = w * 3 + j;
        const int nblk = seg >> 1, kcl = seg & 1;
        fsrc[j] = FWH + (long)nblk * 16384 + kcl * 512 + lane * 8;
        fdst[j] = 16384 + seg * 1024;
    }

#define ISSUE(PH)                                                             \
    {                                                                         \
        const int nb_ = (PH) % 3;                                             \
        _Pragma("unroll")                                                     \
        for (int j = 0; j < 2; ++j)                                           \
            __builtin_amdgcn_global_load_lds((gas_p)(asrc[j] + (PH) * 64),    \
                (las_p)(smem[nb_] + adst[j]), 16, 0, 0);                      \
        _Pragma("unroll")                                                     \
        for (int j = 0; j < 3; ++j)                                           \
            __builtin_amdgcn_global_load_lds((gas_p)(fsrc[j] + (long)(PH) * 1024), \
                (las_p)(smem[nb_] + fdst[j]), 16, 0, 0);                      \
    }

#define COMPUTE(PH)                                                           \
    {                                                                         \
        const int nb_ = (PH) % 3;                                             \
        const float* A_ = (const float*)smem[nb_];                            \
        const u16* F_ = (const u16*)(smem[nb_] + 16384);                      \
        _Pragma("unroll")                                                     \
        for (int kc = 0; kc < 2; ++kc) {                                      \
            bf16x8 AH[2], AL[2];                                              \
            _Pragma("unroll")                                                 \
            for (int mi = 0; mi < 2; ++mi) {                                  \
                const int R = m0 + mi * 16 + lr;                              \
                const int c0 = (kc * 8 + quad * 2) ^ (lr & 7);                \
                const f32x4 x0 = *(const f32x4*)&A_[R * 64 + c0 * 4];         \
                const f32x4 x1 = *(const f32x4*)&A_[R * 64 + (c0 ^ 1) * 4];   \
                split8(x0, x1, &AH[mi], &AL[mi]);                             \
            }                                                                 \
            _Pragma("unroll")                                                 \
            for (int nf = 0; nf < 3; ++nf) {                                  \
                const int sb = (((nbb + nf) * 2 + kc)) * 512 + lane * 8;      \
                const bf16x8 bh = *(const bf16x8*)&F_[sb];                    \
                _Pragma("unroll")                                             \
                for (int mi = 0; mi < 2; ++mi) {                              \
                    f32x4 c = acc[mi][nf];                                    \
                    c = MFMA(AH[mi], bh, c);                                  \
                    c = MFMA(AL[mi], bh, c);                                  \
                    acc[mi][nf] = c;                                          \
                }                                                             \
            }                                                                 \
        }                                                                     \
    }

#define WAITV(N)                                                              \
    asm volatile("s_waitcnt vmcnt(" #N ")" ::: "memory");                     \
    __builtin_amdgcn_sched_barrier(0);                                        \
    __builtin_amdgcn_s_barrier();

    f32x4 acc[2][3] = {};

    ISSUE(0); ISSUE(1);
    WAITV(5)

    for (int ph = 0; ph < 14; ++ph) {
        ISSUE(ph + 2);
        __builtin_amdgcn_sched_barrier(0);
        COMPUTE(ph);
        WAITV(5)
    }
    COMPUTE(14);
    WAITV(0)
    COMPUTE(15);

#undef WAITV
#undef COMPUTE
#undef ISSUE

    #pragma unroll
    for (int mi = 0; mi < 2; ++mi) {
        const int tb = t0 + m0 + mi * 16 + quad * 4;
        const int tblk = (t0 + m0 + mi * 16) >> 4;
        #pragma unroll
        for (int nf = 0; nf < 3; ++nf) {
            const int n = (nbb + nf) * 16 + lr;
            const f32x4 a = acc[mi][nf];
            if (n < 128) {
                u16* Hd = (n < 64) ? FQH : FKH;
                u16* Ld = (n < 64) ? FQL : FKL;
                const int h = n & 63;
                const int kc = h >> 5;
                const int lsub = 16 * ((h & 31) >> 3);
                const long base = ((long)(b * 128 + tblk) * 2 + kc) * 512 + (h & 7);
                #pragma unroll
                for (int r = 0; r < 4; ++r) {
                    const float v = a[r];
                    const u16 hi = f2bf(v);
                    const u16 lo = f2bf(v - bf2f(hi));
                    const long o = base + (long)(quad * 4 + r + lsub) * 8;
                    Hd[o] = hi; Ld[o] = lo;
                }
            } else {
                const int h = n - 128;
                const int hblk = h >> 4;
                #pragma unroll
                for (int r = 0; r < 4; ++r) {
                    const int t = tb + r;
                    const long o = ((long)(b * 4 + hblk) * 64 + (t >> 5)) * 512
                                 + (long)(16 * ((t & 31) >> 3) + (h & 15)) * 8 + (t & 7);
                    VF[o] = f2bf(a[r]);
                }
            }
        }
    }
}

// ---------------------------------------------------------------------------
// stats: D_s = sum_{t>=s} exp(q_t.k_s) AND stores P = exp (masked, bf16)
// in A-fragment layout.  SWAPPED MFMA: cc = mfma(K, Q) -> C row=s, col=t:
// thread (w,quad,lr) holds s = s0+sf*16+quad*4+r (consecutive in r),
// t = jt*64+w*16+lr.  Quartets packed -> 8B LDS writes into swizzled 64x64
// tile (chunk8 = (s>>3)^(t&7); write 2 lanes/bank = free), barrier, read
// back as A-frags (ds_read_b128, 16B-aligned) -> 2 coalesced 16B global
// stores per thread per jt (was 16 scalar 2B).  D: reduce over t = shfl_xor
// 1/2/4/8 within 16-lane groups at the end; red[4][64] + atomicAdd.
// Grid (144, B): s-tile i, t-chunk x (<=4 t-tiles).
// ---------------------------------------------------------------------------
__global__ __launch_bounds__(256, 4) void stats_kernel(
    const u16* __restrict__ FQH, const u16* __restrict__ FQL,
    const u16* __restrict__ FKH, const u16* __restrict__ FKL,
    u16* __restrict__ PF, float* __restrict__ D)
{
    __shared__ float red[4][64];
    __shared__ __align__(16) u16 p_l[64 * 64];     // swizzled [t_sub][s_sub]
    const int tid = threadIdx.x;
    const int w = tid >> 6, lr = tid & 15, quad = (tid >> 4) & 3;
    const int lane = tid & 63;
    const int b = blockIdx.y;
    int x = blockIdx.x, i = 0;
    for (;;) { const int nc = (35 - i) >> 2; if (x < nc) break; x -= nc; ++i; }
    const int s0 = i * 64;
    const int jt0 = i + 4 * x, jt1 = min(jt0 + 4, 32);

    // K frags hoisted: A-operand rows = s.  sf = s-subtile 0..3.
    bf16x8 KH[4][2], KL[4][2];
    #pragma unroll
    for (int sf = 0; sf < 4; ++sf) {
        const long kb = ((long)(b * 128 + i * 4 + sf) * 2) * 512 + lane * 8;
        KH[sf][0] = *(const bf16x8*)&FKH[kb];
        KH[sf][1] = *(const bf16x8*)&FKH[kb + 512];
        KL[sf][0] = *(const bf16x8*)&FKL[kb];
        KL[sf][1] = *(const bf16x8*)&FKL[kb + 512];
    }

    float dsum[4][4] = {};
    for (int jt = jt0; jt < jt1; ++jt) {
        // Q frags for this wave's t-subtile (B-operand cols = t).
        const long qb = ((long)(b * 128 + jt * 4 + w) * 2) * 512 + lane * 8;
        const bf16x8 qh0 = *(const bf16x8*)&FQH[qb];
        const bf16x8 qh1 = *(const bf16x8*)&FQH[qb + 512];
        const bf16x8 ql0 = *(const bf16x8*)&FQL[qb];
        const bf16x8 ql1 = *(const bf16x8*)&FQL[qb + 512];
        const bool diag = (jt == i);
        const int t_sub = w * 16 + lr;
        #pragma unroll
        for (int sf = 0; sf < 4; ++sf) {
            f32x4 cc = {};
            cc = MFMA(KH[sf][0], qh0, cc);
            cc = MFMA(KH[sf][0], ql0, cc);
            cc = MFMA(KL[sf][0], qh0, cc);
            cc = MFMA(KH[sf][1], qh1, cc);
            cc = MFMA(KH[sf][1], ql1, cc);
            cc = MFMA(KL[sf][1], qh1, cc);

            u16 hq[4];
            #pragma unroll
            for (int r = 0; r < 4; ++r) {
                float ev = __expf(cc[r]);
                if (diag && (t_sub < sf * 16 + quad * 4 + r)) ev = 0.f;
                dsum[sf][r] += ev;
                hq[r] = f2bf(ev);
            }
            // pack quartet -> one 8B LDS write (swizzled)
            const int s_sub = sf * 16 + quad * 4;
            const int ch = (s_sub >> 3) ^ (t_sub & 7);
            const int aoff = t_sub * 64 + ch * 8 + (s_sub & 7);
            uint2 pk;
            pk.x = (unsigned)hq[0] | ((unsigned)hq[1] << 16);
            pk.y = (unsigned)hq[2] | ((unsigned)hq[3] << 16);
            *(uint2*)&p_l[aoff] = pk;
        }
        __syncthreads();
        // read back as A-fragments, 2 coalesced 16B stores (tt = w, kcp 0/1)
        #pragma unroll
        for (int kcp = 0; kcp < 2; ++kcp) {
            const int row = w * 16 + (lane & 15);
            const int sc = kcp * 32 + (lane >> 4) * 8;
            const int ch = (sc >> 3) ^ (row & 7);
            const bf16x8 v = *(const bf16x8*)&p_l[row * 64 + ch * 8];
            const long o = ((long)(b * 128 + jt * 4 + w) * 64 + i * 2 + kcp) * 512
                         + lane * 8;
            *(bf16x8*)&PF[o] = v;
        }
        __syncthreads();   // p_l reused next jt
    }

    // D reduction: sum over t.  Within a 16-lane group all lanes share
    // (sf,quad,r)->s; reduce over lr bits.
    #pragma unroll
    for (int sf = 0; sf < 4; ++sf)
        #pragma unroll
        for (int r = 0; r < 4; ++r) {
            float v = dsum[sf][r];
            v += __shfl_xor(v, 1);
            v += __shfl_xor(v, 2);
            v += __shfl_xor(v, 4);
            v += __shfl_xor(v, 8);
            dsum[sf][r] = v;
        }
    if (lr == 0) {
        #pragma unroll
        for (int sf = 0; sf < 4; ++sf)
            #pragma unroll
            for (int r = 0; r < 4; ++r)
                red[w][sf * 16 + quad * 4 + r] = dsum[sf][r];
    }
    __syncthreads();
    if (tid < 64)
        atomicAdd(&D[b * 2048 + s0 + tid],
                  red[0][tid] + red[1][tid] + red[2][tid] + red[3][tid]);
}

// ---------------------------------------------------------------------------
// vscale: VF (B-fragment layout) *= 1/D[s].
// ---------------------------------------------------------------------------
__global__ __launch_bounds__(256) void vscale_kernel(
    u16* __restrict__ VF, const float* __restrict__ D)
{
    const int g = blockIdx.x * 256 + threadIdx.x;   // 131072 threads x 8 u16
    const long e = (long)g * 8;
    const int lane = (int)((e >> 3) & 63);
    const int kc   = (int)((e >> 9) & 63);
    const int b    = (int)(e >> 17);
    const int s = kc * 32 + (lane >> 4) * 8;
    const float4 d0 = *(const float4*)&D[b * 2048 + s];
    const float4 d1 = *(const float4*)&D[b * 2048 + s + 4];
    const float dv[8] = {d0.x, d0.y, d0.z, d0.w, d1.x, d1.y, d1.z, d1.w};
    bf16x8 vv = *(bf16x8*)&VF[e];
    bf16x8 ov;
    #pragma unroll
    for (int j = 0; j < 8; ++j)
        ov[j] = (short)f2bf(bf2f((u16)vv[j]) / dv[j]);
    *(bf16x8*)&VF[e] = ov;
}

// ---------------------------------------------------------------------------
// out: pure streaming PV GEMM.  out[t][h] = sum_{s<=t} P[t][s] * Vtilde[s][h].
// Grid (80, B): t-tile i, s-chunk c (<=8 s-tiles).
// ---------------------------------------------------------------------------
__global__ __launch_bounds__(256, 4) void out_kernel(
    const u16* __restrict__ PF, const u16* __restrict__ VF,
    float* __restrict__ out)
{
    const int tid = threadIdx.x;
    const int w = tid >> 6, lr = tid & 15, quad = (tid >> 4) & 3;
    const int lane = tid & 63;
    const int b = blockIdx.y;
    int x = blockIdx.x, i = 0;
    for (;;) { const int nc = (i + 8) >> 3; if (x < nc) break; x -= nc; ++i; }
    const int t0 = i * 64;
    const int js0 = 8 * x, js1 = min(8 * x + 8, i + 1);
    const int tblk = i * 4 + w;

    f32x4 oacc[4] = {};
    for (int js = js0; js < js1; ++js) {
        const long pb = ((long)(b * 128 + tblk) * 64 + 2 * js) * 512 + lane * 8;
        const bf16x8 a0 = *(const bf16x8*)&PF[pb];
        const bf16x8 a1 = *(const bf16x8*)&PF[pb + 512];
        #pragma unroll
        for (int nf = 0; nf < 4; ++nf) {
            const long vb = ((long)(b * 4 + nf) * 64 + 2 * js) * 512 + lane * 8;
            const bf16x8 v0 = *(const bf16x8*)&VF[vb];
            const bf16x8 v1 = *(const bf16x8*)&VF[vb + 512];
            oacc[nf] = MFMA(a0, v0, oacc[nf]);
            oacc[nf] = MFMA(a1, v1, oacc[nf]);
        }
    }

    const bool single = (i < 8);   // one chunk covers the whole row
    #pragma unroll
    for (int nf = 0; nf < 4; ++nf) {
        const int h = nf * 16 + lr;
        #pragma unroll
        for (int r = 0; r < 4; ++r) {
            const int t = t0 + w * 16 + quad * 4 + r;
            const long o = (long)(b * 2048 + t) * 64 + h;
            if (single) out[o] = oacc[nf][r];
            else        atomicAdd(&out[o], oacc[nf][r]);
        }
    }
}

extern "C" void kernel_launch(void* const* d_in, const int* in_sizes, int n_in,
                              void* d_out, int out_size, void* d_ws, size_t ws_size,
                              hipStream_t stream)
{
    const float* idx = (const float*)d_in[0];
    const float* Wk  = (const float*)d_in[1];
    const float* Wq  = (const float*)d_in[2];
    const float* Wv  = (const float*)d_in[3];
    char* ws = (char*)d_ws;
    float* out = (float*)d_out;

    u16* FWH = (u16*)(ws + WH_OFF);
    u16* FQH = (u16*)(ws + FQH_OFF); u16* FQL = (u16*)(ws + FQL_OFF);
    u16* FKH = (u16*)(ws + FKH_OFF); u16* FKL = (u16*)(ws + FKL_OFF);
    u16* VF  = (u16*)(ws + VF_OFF);
    float* Dp = (float*)(ws + DD_OFF);
    u16* PF  = (u16*)(ws + PF_OFF);

    hipMemsetAsync(out, 0, (size_t)8 * 2048 * 64 * sizeof(float), stream);
    hipMemsetAsync(Dp, 0, (size_t)8 * 2048 * sizeof(float), stream);

    wsplit_kernel<<<192, 128, 0, stream>>>(Wk, Wq, Wv, FWH);
    qkv_kernel<<<256, 512, 0, stream>>>(idx, FWH, FQH, FQL, FKH, FKL, VF);
    stats_kernel<<<dim3(144, 8), 256, 0, stream>>>(FQH, FQL, FKH, FKL, PF, Dp);
    vscale_kernel<<<512, 256, 0, stream>>>(VF, Dp);
    out_kernel<<<dim3(80, 8), 256, 0, stream>>>(PF, VF, out);
}